// Round 8
// baseline (544.521 us; speedup 1.0000x reference)
//
#include <hip/hip_runtime.h>
#include <hip/hip_bf16.h>

#define DD 1024
#define NB 4
#define TT 1024
#define NH 16
#define NS 4
#define LKV 1028   // NS + TT
#define NCH 4
#define CHS 257    // keys per chunk (4*257 = 1028)
#define GRID_N 256

typedef __hip_bfloat16 bf16;
typedef __attribute__((ext_vector_type(8))) short short8;
typedef __attribute__((ext_vector_type(4))) float f32x4;

#define GLD16(gp, lp) __builtin_amdgcn_global_load_lds( \
    (const __attribute__((address_space(1))) unsigned int*)(const void*)(gp), \
    (__attribute__((address_space(3))) unsigned int*)(void*)(lp), 16, 0, 0)

__device__ __forceinline__ float warp_sum(float v) {
#pragma unroll
    for (int o = 32; o > 0; o >>= 1) v += __shfl_xor(v, o);
    return v;
}

__device__ __forceinline__ float b2f(unsigned short u) {
    union { unsigned int i; float f; } x; x.i = ((unsigned)u) << 16; return x.f;
}
__device__ __forceinline__ unsigned short f2b(float f) {
    bf16 h = __float2bfloat16(f);
    union { bf16 h; unsigned short u; } x; x.h = h; return x.u;
}

// ================= prep: cvt x + 6 weights, PE table, state copy, ctr zero ====
struct PrepArgs {
    const float* cin[7];   // x, seW, oeW, sWk, sWv, oWk, oWv
    bf16* cout[7];
    const float* state0;
    float* cat;
    float* pe;
    int* ctr;
};

__global__ __launch_bounds__(256) void prep_kernel(PrepArgs a) {
    int bid = blockIdx.x;
    int tid = threadIdx.x;
    if (bid < 10240) {
        const float* in; bf16* out; size_t off;
        if (bid < 4096) { in = a.cin[0]; out = a.cout[0]; off = (size_t)bid * 1024; }
        else {
            int w = (bid - 4096) >> 10;
            in = a.cin[1 + w]; out = a.cout[1 + w];
            off = (size_t)((bid - 4096) & 1023) * 1024;
        }
        size_t i = off + tid * 4;
        float4 v = *(const float4*)(in + i);
        out[i + 0] = __float2bfloat16(v.x);
        out[i + 1] = __float2bfloat16(v.y);
        out[i + 2] = __float2bfloat16(v.z);
        out[i + 3] = __float2bfloat16(v.w);
    } else if (bid < 11264) {
        int t = bid - 10240;
#pragma unroll
        for (int i = 0; i < 2; ++i) {
            int j = i * 256 + tid;                       // 0..511
            float ang = (float)t * exp2f(-(float)j * (1.0f / 256.0f));
            a.pe[(size_t)t * DD + j]       = sinf(ang);
            a.pe[(size_t)t * DD + 512 + j] = cosf(ang);
        }
    } else if (bid < 11280) {
        int r = bid - 11264;       // 0..15
        int b = r >> 2, s = r & 3;
#pragma unroll
        for (int i = 0; i < 4; ++i)
            a.cat[(size_t)(b * LKV + s) * DD + i * 256 + tid] =
                a.state0[(size_t)r * DD + i * 256 + tid];
    } else {
        if (tid < 32) a.ctr[tid] = 0;   // grid-barrier counters
    }
}

// ================= fused LayerNorm -> bf16 (state-kv rows + out token rows) ===
__global__ __launch_bounds__(256) void ln_fused_kernel(
    const float* __restrict__ cat, const float* __restrict__ cat2,
    bf16* __restrict__ lnbb, bf16* __restrict__ lnbb2,
    const float* __restrict__ sg, const float* __restrict__ sb,
    const float* __restrict__ og, const float* __restrict__ ob)
{
    int bid = blockIdx.x;
    int tid = threadIdx.x;
    const float* in; bf16* out; const float* g; const float* b;
    if (bid < 4112) {
        in = cat + (size_t)bid * DD; out = lnbb + (size_t)bid * DD; g = sg; b = sb;
    } else {
        int r = bid - 4112;
        int row = (r >> 10) * LKV + (r & 1023);
        in = cat2 + (size_t)row * DD; out = lnbb2 + (size_t)r * DD; g = og; b = ob;
    }
    float v[4];
    float s1 = 0.f, s2 = 0.f;
#pragma unroll
    for (int i = 0; i < 4; ++i) {
        v[i] = in[i * 256 + tid];
        s1 += v[i]; s2 += v[i] * v[i];
    }
    s1 = warp_sum(s1); s2 = warp_sum(s2);
    __shared__ float a1[4], a2[4];
    int w = tid >> 6;
    if ((tid & 63) == 0) { a1[w] = s1; a2[w] = s2; }
    __syncthreads();
    s1 = a1[0] + a1[1] + a1[2] + a1[3];
    s2 = a2[0] + a2[1] + a2[2] + a2[3];
    float mu  = s1 * (1.0f / DD);
    float var = s2 * (1.0f / DD) - mu * mu;
    var = var < 0.f ? 0.f : var;
    float rs = rsqrtf(var + 1e-5f);
#pragma unroll
    for (int i = 0; i < 4; ++i) {
        int c = i * 256 + tid;
        out[c] = __float2bfloat16((v[i] - mu) * rs * g[c] + b[c]);
    }
}

// ================= MFMA tile body (128x128, BK=32, 4 waves) ===================
__device__ __forceinline__ void mfma_tile(
    const bf16* __restrict__ A, const bf16* __restrict__ W,
    const float* __restrict__ bias,
    float* __restrict__ outf, bf16* __restrict__ outb,
    int M, int obs, int oro, const float* __restrict__ pe,
    bf16* As, bf16* Ws, int m0, int n0)
{
    int tid  = threadIdx.x;
    int lane = tid & 63;
    int wave = tid >> 6;
    int wm = (wave >> 1) << 6;
    int wn = (wave & 1) << 6;

    f32x4 acc[4][4] = {};

    int soff  = wave * 1024 + lane * 16;
    int srow  = soff >> 6;
    int scol  = (soff & 63) >> 1;
    char* lA0 = (char*)As + wave * 1024;
    char* lA1 = (char*)As + 4096 + wave * 1024;
    char* lW0 = (char*)Ws + wave * 1024;
    char* lW1 = (char*)Ws + 4096 + wave * 1024;

    int fRow = lane & 15;
    int kOff = (lane >> 4) << 3;

    for (int k0 = 0; k0 < DD; k0 += 32) {
        GLD16(A + (size_t)(m0 + srow) * DD + k0 + scol,      lA0);
        GLD16(A + (size_t)(m0 + 64 + srow) * DD + k0 + scol, lA1);
        GLD16(W + (size_t)(n0 + srow) * DD + k0 + scol,      lW0);
        GLD16(W + (size_t)(n0 + 64 + srow) * DD + k0 + scol, lW1);
        __syncthreads();
        short8 a[4], b[4];
#pragma unroll
        for (int mi = 0; mi < 4; ++mi)
            a[mi] = *(const short8*)(As + (wm + mi * 16 + fRow) * 32 + kOff);
#pragma unroll
        for (int ni = 0; ni < 4; ++ni)
            b[ni] = *(const short8*)(Ws + (wn + ni * 16 + fRow) * 32 + kOff);
#pragma unroll
        for (int mi = 0; mi < 4; ++mi)
#pragma unroll
            for (int ni = 0; ni < 4; ++ni)
                acc[mi][ni] = __builtin_amdgcn_mfma_f32_16x16x32_bf16(
                    a[mi], b[ni], acc[mi][ni], 0, 0, 0);
        __syncthreads();
    }

    int cCol  = lane & 15;
    int cRow4 = (lane >> 4) << 2;
#pragma unroll
    for (int mi = 0; mi < 4; ++mi) {
#pragma unroll
        for (int ni = 0; ni < 4; ++ni) {
#pragma unroll
            for (int r = 0; r < 4; ++r) {
                int row = m0 + wm + mi * 16 + cRow4 + r;
                int col = n0 + wn + ni * 16 + cCol;
                if (row < M) {
                    float v = acc[mi][ni][r] + bias[col];
                    if (outf) {
                        v += pe[(size_t)(row & 1023) * DD + col];
                        int orow = (row >> 10) * obs + oro + (row & 1023);
                        outf[(size_t)orow * DD + col] = v;
                    } else {
                        int orow = obs ? ((row >> 10) * obs + (row & 1023)) : row;
                        outb[(size_t)orow * DD + col] = __float2bfloat16(v);
                    }
                }
            }
        }
    }
}

// ================= fused embeds, XCD-swizzled linear grid (512 blocks) ========
__global__ __launch_bounds__(256) void embed_fused_kernel(
    const bf16* __restrict__ xb,
    const bf16* __restrict__ seW, const bf16* __restrict__ oeW,
    const float* __restrict__ seb, const float* __restrict__ oeb,
    float* __restrict__ cat, float* __restrict__ cat2,
    const float* __restrict__ pe)
{
    __shared__ bf16 As[128 * 32];
    __shared__ bf16 Ws[128 * 32];
    int bid = blockIdx.x;
    int t = (bid & 7) * 64 + (bid >> 3);   // bijective XCD swizzle (512 = 8*64)
    int x = t & 7;
    int q = t >> 3;
    int z = q & 1;
    int y = q >> 1;
    const bf16* W = z ? oeW : seW;
    const float* bias = z ? oeb : seb;
    float* outf = z ? cat2 : cat;
    int oro = z ? 0 : NS;
    mfma_tile(xb, W, bias, outf, nullptr, 4096, LKV, oro, pe, As, Ws,
              y * 128, x * 128);
}

// ================= fused K/V GEMMs, XCD-swizzled linear grid (1056 blocks) ====
__global__ __launch_bounds__(256) void kv_fused_kernel(
    const bf16* __restrict__ lnbb, const bf16* __restrict__ lnbb2,
    const bf16* __restrict__ W0, const bf16* __restrict__ W1,
    const bf16* __restrict__ W2, const bf16* __restrict__ W3,
    const float* __restrict__ b0, const float* __restrict__ b1,
    const float* __restrict__ b2, const float* __restrict__ b3,
    bf16* __restrict__ o0, bf16* __restrict__ o1,
    bf16* __restrict__ o2, bf16* __restrict__ o3)
{
    __shared__ bf16 As[128 * 32];
    __shared__ bf16 Ws[128 * 32];
    int bid = blockIdx.x;
    int t = (bid & 7) * 132 + (bid >> 3);  // bijective XCD swizzle (1056 = 8*132)
    int x = t & 7;
    int u = t >> 3;          // 0..131
    int zi = u & 1;
    int v = u >> 1;          // 0..65
    int y = v % 33;
    int zp = v / 33;
    int z = zp * 2 + zi;
    const bf16* Warr[4] = {W0, W1, W2, W3};
    const float* barr[4] = {b0, b1, b2, b3};
    bf16* oarr[4] = {o0, o1, o2, o3};
    const bf16* A = (zp == 0) ? lnbb : lnbb2;
    int M   = (zp == 0) ? 4112 : 4096;
    int obs = (zp == 0) ? 0 : LKV;
    mfma_tile(A, Warr[z], barr[z], nullptr, oarr[z], M, obs, 0, nullptr, As, Ws,
              y * 128, x * 128);
}

// ============ small GEMM with fused input LayerNorm (standalone, q2 proj) =====
template<int M>
__global__ __launch_bounds__(256) void small_ln_gemm_kernel(
    const float* __restrict__ A, int row0, int rstride,
    const float* __restrict__ lng, const float* __restrict__ lnb,
    const float* __restrict__ W, const float* __restrict__ bias,
    float* __restrict__ outf)
{
    __shared__ float As[M * DD];
    __shared__ float smu[M], srs[M];
    int tid = threadIdx.x;
    int lane = tid & 63;
    int w = tid >> 6;
#pragma unroll
    for (int i = 0; i < M; ++i) {
        int row = row0 + i * rstride;
        *(float4*)(As + i * DD + tid * 4) =
            *(const float4*)(A + (size_t)row * DD + tid * 4);
    }
    __syncthreads();
    constexpr int RPW = (M + 3) / 4;
#pragma unroll
    for (int i = 0; i < RPW; ++i) {
        int r = w * RPW + i;
        if (r < M) {
            float s1 = 0.f, s2 = 0.f;
#pragma unroll
            for (int j = 0; j < 4; ++j) {
                float4 v = *(const float4*)(As + r * DD + (j * 64 + lane) * 4);
                s1 += v.x + v.y + v.z + v.w;
                s2 += v.x*v.x + v.y*v.y + v.z*v.z + v.w*v.w;
            }
            s1 = warp_sum(s1); s2 = warp_sum(s2);
            if (lane == 0) {
                float mu = s1 * (1.0f / DD);
                float var = s2 * (1.0f / DD) - mu * mu;
                var = var < 0.f ? 0.f : var;
                smu[r] = mu; srs[r] = rsqrtf(var + 1e-5f);
            }
        }
    }
    __syncthreads();
    float4 gv = *(const float4*)(lng + tid * 4);
    float4 bv = *(const float4*)(lnb + tid * 4);
#pragma unroll
    for (int i = 0; i < M; ++i) {
        float mu = smu[i], rs = srs[i];
        float4 v = *(const float4*)(As + i * DD + tid * 4);
        v.x = (v.x - mu) * rs * gv.x + bv.x;
        v.y = (v.y - mu) * rs * gv.y + bv.y;
        v.z = (v.z - mu) * rs * gv.z + bv.z;
        v.w = (v.w - mu) * rs * gv.w + bv.w;
        *(float4*)(As + i * DD + tid * 4) = v;
    }
    __syncthreads();
    int n = blockIdx.x * 4 + w;
    const float* Wr = W + (size_t)n * DD;
    float acc[M] = {};
#pragma unroll
    for (int j = 0; j < 4; ++j) {
        float4 wv = *(const float4*)(Wr + j * 256 + lane * 4);
#pragma unroll
        for (int m = 0; m < M; ++m) {
            float4 av = *(const float4*)(As + m * DD + j * 256 + lane * 4);
            acc[m] += av.x * wv.x + av.y * wv.y + av.z * wv.z + av.w * wv.w;
        }
    }
#pragma unroll
    for (int m = 0; m < M; ++m) acc[m] = warp_sum(acc[m]);
    if (lane == 0) {
#pragma unroll
        for (int m = 0; m < M; ++m)
            outf[(size_t)m * DD + n] = acc[m] + bias[n];
    }
}

// ================= copy lo[:, -1] =============================================
__global__ __launch_bounds__(256) void copy_lolast_kernel(
    const float* __restrict__ cat2, float* __restrict__ dst)
{
    int b = blockIdx.x;
    int tid = threadIdx.x;
#pragma unroll
    for (int i = 0; i < 4; ++i)
        dst[(size_t)b * DD + i * 256 + tid] =
            cat2[(size_t)(b * LKV + (TT - 1)) * DD + i * 256 + tid];
}

// ================= mega kernel: everything after kv_fused =====================
struct MegaArgs {
    const float *state0, *s_lnq_g, *s_lnq_b, *s_Wq, *s_bq;
    float *qh_s;
    const bf16 *kh, *vh;
    float *pm, *pl, *pacc;
    const float *s_Wo, *s_bo;
    float *lat1;
    const float *s_lnffn_g, *s_lnffn_b, *s_fc1_W, *s_fc1_b;
    float *g1;
    const float *s_fc2_W, *s_fc2_b;
    float *lat2;
    const float *s_lnslot_g, *s_lnslot_b, *slot_ctx;
    float *stateNew;
    const float *o_lnkv_g, *o_lnkv_b, *o_Wk, *o_bk, *o_Wv, *o_bv;
    bf16 *kh2, *vh2;
    const float *q2h;
    const float *o_Wo, *o_bo, *lo_last;
    float *lo1;
    const float *o_lnffn_g, *o_lnffn_b, *o_fc1_W, *o_fc1_b;
    float *g2;
    const float *o_fc2_W, *o_fc2_b;
    float *lo2;
    const float *op_W, *op_b;
    float *dout;
    int *ctr;
};

__device__ __forceinline__ void gsync(int* ctr, int id) {
    __syncthreads();
    if (threadIdx.x == 0) {
        __threadfence();
        __hip_atomic_fetch_add(ctr + id, 1, __ATOMIC_ACQ_REL, __HIP_MEMORY_SCOPE_AGENT);
        int spins = 0;
        while (__hip_atomic_load(ctr + id, __ATOMIC_ACQUIRE, __HIP_MEMORY_SCOPE_AGENT)
                   < GRID_N && ++spins < 20000000) {}
    }
    __syncthreads();
}

// stage M rows of A (row0 + i*rstride), LayerNorm them, store bf16 into Asb
template<int M>
__device__ void stage_rows_ln_bf16(
    const float* A, int row0, int rstride,
    const float* lng, const float* lnb,
    bf16* Asb, float* part1, float* part2)
{
    int tid = threadIdx.x, lane = tid & 63, w = tid >> 6;
#pragma unroll
    for (int i = 0; i < M; ++i) {
        const float* row = A + (size_t)(row0 + i * rstride) * DD;
        float4 v = *(const float4*)(row + tid * 4);
        float s1 = v.x + v.y + v.z + v.w;
        float s2 = v.x*v.x + v.y*v.y + v.z*v.z + v.w*v.w;
        s1 = warp_sum(s1); s2 = warp_sum(s2);
        if (lane == 0) { part1[i * 4 + w] = s1; part2[i * 4 + w] = s2; }
    }
    __syncthreads();
    float4 gv = *(const float4*)(lng + tid * 4);
    float4 bv = *(const float4*)(lnb + tid * 4);
#pragma unroll
    for (int i = 0; i < M; ++i) {
        float s1 = part1[i*4+0] + part1[i*4+1] + part1[i*4+2] + part1[i*4+3];
        float s2 = part2[i*4+0] + part2[i*4+1] + part2[i*4+2] + part2[i*4+3];
        float mu = s1 * (1.0f / DD);
        float var = s2 * (1.0f / DD) - mu * mu;
        var = var < 0.f ? 0.f : var;
        float rs = rsqrtf(var + 1e-5f);
        const float* row = A + (size_t)(row0 + i * rstride) * DD;
        float4 v = *(const float4*)(row + tid * 4);
        ushort4 o;
        o.x = f2b((v.x - mu) * rs * gv.x + bv.x);
        o.y = f2b((v.y - mu) * rs * gv.y + bv.y);
        o.z = f2b((v.z - mu) * rs * gv.z + bv.z);
        o.w = f2b((v.w - mu) * rs * gv.w + bv.w);
        *(ushort4*)(Asb + i * DD + tid * 4) = o;
    }
    __syncthreads();
}

template<int M>
__device__ void stage_rows_plain_bf16(const float* A, bf16* Asb)
{
    int tid = threadIdx.x;
#pragma unroll
    for (int i = 0; i < M; ++i) {
        float4 v = *(const float4*)(A + (size_t)i * DD + tid * 4);
        ushort4 o;
        o.x = f2b(v.x); o.y = f2b(v.y); o.z = f2b(v.z); o.w = f2b(v.w);
        *(ushort4*)(Asb + i * DD + tid * 4) = o;
    }
    __syncthreads();
}

// combine split-K attention partials directly into Asb (rows = b*LQ+qi)
template<int LQ>
__device__ void stage_combine(const float* pm, const float* pl,
                              const float* pacc, bf16* Asb)
{
    int tid = threadIdx.x;
    for (int idx = tid; idx < LQ * 4 * 256; idx += 256) {
        int m  = idx >> 8;
        int n4 = (idx & 255) * 4;
        int b = m / LQ, qi = m - b * LQ;
        int h = n4 >> 6, d = n4 & 63;
        int base = ((b * 16 + h) * 4 + qi) * NCH;
        float m0 = pm[base], m1 = pm[base+1], m2 = pm[base+2], m3 = pm[base+3];
        float Mx = fmaxf(fmaxf(m0, m1), fmaxf(m2, m3));
        float w0 = expf(m0-Mx), w1 = expf(m1-Mx), w2 = expf(m2-Mx), w3 = expf(m3-Mx);
        float L = pl[base]*w0 + pl[base+1]*w1 + pl[base+2]*w2 + pl[base+3]*w3;
        float inv = 1.f / L;
        float4 a0 = *(const float4*)(pacc + (size_t)(base+0)*64 + d);
        float4 a1 = *(const float4*)(pacc + (size_t)(base+1)*64 + d);
        float4 a2 = *(const float4*)(pacc + (size_t)(base+2)*64 + d);
        float4 a3 = *(const float4*)(pacc + (size_t)(base+3)*64 + d);
        ushort4 o;
        o.x = f2b((a0.x*w0 + a1.x*w1 + a2.x*w2 + a3.x*w3) * inv);
        o.y = f2b((a0.y*w0 + a1.y*w1 + a2.y*w2 + a3.y*w3) * inv);
        o.z = f2b((a0.z*w0 + a1.z*w1 + a2.z*w2 + a3.z*w3) * inv);
        o.w = f2b((a0.w*w0 + a1.w*w1 + a2.w*w2 + a3.w*w3) * inv);
        *(ushort4*)(Asb + m * DD + n4) = o;
    }
    __syncthreads();
}

// GEMM from bf16-staged A: out[m][n] = dot + bias (+gelu) (+res)
template<int M>
__device__ void gemm_stage(const bf16* Asb, const float* W, const float* bias,
                           float* outf, const float* res, int gelu, int n)
{
    int lane = threadIdx.x & 63;
    const float* Wr = W + (size_t)n * DD;
    float acc[M] = {};
#pragma unroll
    for (int j = 0; j < 4; ++j) {
        float4 wv = *(const float4*)(Wr + j * 256 + lane * 4);
#pragma unroll
        for (int m = 0; m < M; ++m) {
            ushort4 av = *(const ushort4*)(Asb + m * DD + j * 256 + lane * 4);
            acc[m] += b2f(av.x)*wv.x + b2f(av.y)*wv.y
                    + b2f(av.z)*wv.z + b2f(av.w)*wv.w;
        }
    }
#pragma unroll
    for (int m = 0; m < M; ++m) acc[m] = warp_sum(acc[m]);
    if (lane == 0) {
#pragma unroll
        for (int m = 0; m < M; ++m) {
            float v = acc[m] + bias[n];
            if (gelu) v = 0.5f * v * (1.0f + erff(v * 0.70710678118654752f));
            if (res)  v += res[(size_t)m * DD + n];
            outf[(size_t)m * DD + n] = v;
        }
    }
}

// paired K/V columns from LN'd state rows -> kh2/vh2 (remapped rows, bf16)
__device__ void kv_cols_stage(const bf16* Asb,
    const float* Wk, const float* bk, const float* Wv, const float* bv,
    bf16* kh2, bf16* vh2, int n)
{
    int lane = threadIdx.x & 63;
    const float* WrK = Wk + (size_t)n * DD;
    const float* WrV = Wv + (size_t)n * DD;
    float accK[16] = {}, accV[16] = {};
#pragma unroll
    for (int j = 0; j < 4; ++j) {
        float4 wk4 = *(const float4*)(WrK + j * 256 + lane * 4);
        float4 wv4 = *(const float4*)(WrV + j * 256 + lane * 4);
#pragma unroll
        for (int m = 0; m < 16; ++m) {
            ushort4 av = *(const ushort4*)(Asb + m * DD + j * 256 + lane * 4);
            float ax = b2f(av.x), ay = b2f(av.y), az = b2f(av.z), aw = b2f(av.w);
            accK[m] += ax*wk4.x + ay*wk4.y + az*wk4.z + aw*wk4.w;
            accV[m] += ax*wv4.x + ay*wv4.y + az*wv4.z + aw*wv4.w;
        }
    }
#pragma unroll
    for (int m = 0; m < 16; ++m) { accK[m] = warp_sum(accK[m]); accV[m] = warp_sum(accV[m]); }
    if (lane == 0) {
#pragma unroll
        for (int m = 0; m < 16; ++m) {
            int orow = (m >> 2) * LKV + TT + (m & 3);
            kh2[(size_t)orow * DD + n] = __float2bfloat16(accK[m] + bk[n]);
            vh2[(size_t)orow * DD + n] = __float2bfloat16(accV[m] + bv[n]);
        }
    }
}

// split-K attention partial (same mapping as round-7 kernel), smem overlay
template<int LQ>
__device__ void attn_part_stage(
    const float* qh, const bf16* kh, const bf16* vh,
    float* pm, float* pl, float* pacc, char* smem)
{
    float* qs    = (float*)smem;            // [4][64]
    float* sc    = qs + 4 * 64;             // [4][257]
    float* redm  = sc + 4 * 257;            // [4][4]
    float* redl  = redm + 16;               // [4][4]
    float* paccs = redl + 16;               // [4][4][64]
    int blk = blockIdx.x;
    int c  = blk & (NCH - 1);
    int bh = blk >> 2;
    int b = bh >> 4, h = bh & 15;
    int tid = threadIdx.x;
    int lane = tid & 63, w = tid >> 6;

    if (w < LQ) qs[w * 64 + lane] = qh[(size_t)(b * LQ + w) * DD + h * 64 + lane];
    __syncthreads();

    int kbeg = c * CHS;
    for (int t = tid; t < CHS; t += 256) {
        const ushort4* kr = (const ushort4*)((const unsigned short*)kh
            + (size_t)(b * LKV + kbeg + t) * DD + h * 64);
        float kf[64];
#pragma unroll
        for (int i = 0; i < 16; ++i) {
            ushort4 kk = kr[i];
            kf[i*4+0] = b2f(kk.x); kf[i*4+1] = b2f(kk.y);
            kf[i*4+2] = b2f(kk.z); kf[i*4+3] = b2f(kk.w);
        }
#pragma unroll
        for (int qi = 0; qi < LQ; ++qi) {
            float s = 0.f;
#pragma unroll
            for (int d = 0; d < 64; ++d) s += qs[qi * 64 + d] * kf[d];
            sc[qi * 257 + t] = s * 0.125f;
        }
    }
    __syncthreads();

    float M[LQ], L[LQ];
#pragma unroll
    for (int qi = 0; qi < LQ; ++qi) {
        float lm = -1e30f;
        for (int t = tid; t < CHS; t += 256) lm = fmaxf(lm, sc[qi * 257 + t]);
#pragma unroll
        for (int o = 32; o > 0; o >>= 1) lm = fmaxf(lm, __shfl_xor(lm, o));
        if (lane == 0) redm[w * 4 + qi] = lm;
    }
    __syncthreads();
#pragma unroll
    for (int qi = 0; qi < LQ; ++qi)
        M[qi] = fmaxf(fmaxf(redm[qi], redm[4 + qi]), fmaxf(redm[8 + qi], redm[12 + qi]));

#pragma unroll
    for (int qi = 0; qi < LQ; ++qi) {
        float ls = 0.f;
        for (int t = tid; t < CHS; t += 256) {
            float e = expf(sc[qi * 257 + t] - M[qi]);
            sc[qi * 257 + t] = e;
            ls += e;
        }
        ls = warp_sum(ls);
        if (lane == 0) redl[w * 4 + qi] = ls;
    }
    __syncthreads();
#pragma unroll
    for (int qi = 0; qi < LQ; ++qi)
        L[qi] = redl[qi] + redl[4 + qi] + redl[8 + qi] + redl[12 + qi];

    {
        int k0 = w * 65;
        int k1 = (k0 + 65 < CHS) ? k0 + 65 : CHS;
        float acc[LQ] = {};
        const unsigned short* vb = (const unsigned short*)vh
            + (size_t)(b * LKV + kbeg) * DD + h * 64 + lane;
        for (int k = k0; k < k1; ++k) {
            float v = b2f(vb[(size_t)k * DD]);
#pragma unroll
            for (int qi = 0; qi < LQ; ++qi) acc[qi] += sc[qi * 257 + k] * v;
        }
#pragma unroll
        for (int qi = 0; qi < LQ; ++qi) paccs[(w * 4 + qi) * 64 + lane] = acc[qi];
    }
    __syncthreads();
    if (tid < 64) {
#pragma unroll
        for (int qi = 0; qi < LQ; ++qi) {
            float s = paccs[qi * 64 + tid] + paccs[(4 + qi) * 64 + tid]
                    + paccs[(8 + qi) * 64 + tid] + paccs[(12 + qi) * 64 + tid];
            pacc[(size_t)((bh * 4 + qi) * NCH + c) * 64 + tid] = s;
        }
    }
    if (tid < LQ) {
        pm[(bh * 4 + tid) * NCH + c] = M[tid];
        pl[(bh * 4 + tid) * NCH + c] = L[tid];
    }
    __syncthreads();
}

__device__ void gate_stage(int b, const MegaArgs& a, float* ex)
{
    int tid = threadIdx.x, lane = tid & 63, w = tid >> 6;
    {
        const float* row = a.lat2 + (size_t)(b * NS + w) * DD;
        float4 v[4];
        float s1 = 0.f, s2 = 0.f;
#pragma unroll
        for (int j = 0; j < 4; ++j) {
            v[j] = *(const float4*)(row + (j * 64 + lane) * 4);
            s1 += v[j].x + v[j].y + v[j].z + v[j].w;
            s2 += v[j].x*v[j].x + v[j].y*v[j].y + v[j].z*v[j].z + v[j].w*v[j].w;
        }
        s1 = warp_sum(s1); s2 = warp_sum(s2);
        float mu = s1 * (1.0f / DD);
        float var = s2 * (1.0f / DD) - mu * mu;
        var = var < 0.f ? 0.f : var;
        float rs = rsqrtf(var + 1e-5f);
        float dot = 0.f;
#pragma unroll
        for (int j = 0; j < 4; ++j) {
            int c = (j * 64 + lane) * 4;
            float4 gv = *(const float4*)(a.s_lnslot_g + c);
            float4 bv = *(const float4*)(a.s_lnslot_b + c);
            float4 cv = *(const float4*)(a.slot_ctx + c);
            dot += ((v[j].x - mu) * rs * gv.x + bv.x) * cv.x
                 + ((v[j].y - mu) * rs * gv.y + bv.y) * cv.y
                 + ((v[j].z - mu) * rs * gv.z + bv.z) * cv.z
                 + ((v[j].w - mu) * rs * gv.w + bv.w) * cv.w;
        }
        dot = warp_sum(dot);
        if (lane == 0) ex[w] = dot;
    }
    __syncthreads();
    if (tid == 0) {
        float l[NS];
        for (int s = 0; s < NS; ++s) l[s] = ex[s];
        int i0 = 0;
        for (int s = 1; s < NS; ++s) if (l[s] > l[i0]) i0 = s;
        int i1 = (i0 == 0) ? 1 : 0;
        for (int s = 0; s < NS; ++s) if (s != i0 && l[s] > l[i1]) i1 = s;
        float mx = fmaxf(l[i0], l[i1]);
        float e0 = expf(l[i0] - mx), e1 = expf(l[i1] - mx);
        float inv = 1.f / (e0 + e1);
        for (int s = 0; s < NS; ++s) ex[4 + s] = 0.f;
        ex[4 + i0] = e0 * inv;
        ex[4 + i1] += e1 * inv;
        a.dout[4096 + b * 2 + 0] = (float)i0;
        a.dout[4096 + b * 2 + 1] = (float)i1;
    }
    __syncthreads();
    for (int idx = tid; idx < NS * DD; idx += 256) {
        int s = idx >> 10;
        float so = a.state0[(size_t)b * NS * DD + idx];
        float lt = a.lat2[(size_t)b * NS * DD + idx];
        float ns = 0.6f * so + 0.4f * ex[4 + s] * tanhf(lt);
        a.stateNew[(size_t)b * NS * DD + idx] = ns;
        a.dout[4104 + b * NS * DD + idx] = ns;
    }
}

__global__ __launch_bounds__(256) void mega_kernel(MegaArgs a)
{
    __shared__ char smem[33536];        // 32KB Asb + partials/extras
    bf16* Asb    = (bf16*)smem;         // [16][1024] bf16 = 32KB
    float* part1 = (float*)(smem + 32768);   // 64
    float* part2 = part1 + 64;               // 64
    float* ex    = part2 + 64;               // gate logits/alpha
    int* ctr = a.ctr;
    int bid = blockIdx.x;
    int w = threadIdx.x >> 6;
    int n = bid * 4 + w;

    // S0: qh_s = LN_q(state) @ sWq
    stage_rows_ln_bf16<16>(a.state0, 0, 1, a.s_lnq_g, a.s_lnq_b, Asb, part1, part2);
    gemm_stage<16>(Asb, a.s_Wq, a.s_bq, a.qh_s, nullptr, 0, n);
    gsync(ctr, 0);
    // S1: state-branch attention partials
    attn_part_stage<4>(a.qh_s, a.kh, a.vh, a.pm, a.pl, a.pacc, smem);
    gsync(ctr, 1);
    // S2: combine + Wo + residual(state)
    stage_combine<4>(a.pm, a.pl, a.pacc, Asb);
    gemm_stage<16>(Asb, a.s_Wo, a.s_bo, a.lat1, a.state0, 0, n);
    gsync(ctr, 2);
    // S3: LN + fc1 + gelu
    stage_rows_ln_bf16<16>(a.lat1, 0, 1, a.s_lnffn_g, a.s_lnffn_b, Asb, part1, part2);
    gemm_stage<16>(Asb, a.s_fc1_W, a.s_fc1_b, a.g1, nullptr, 1, n);
    gsync(ctr, 3);
    // S4: fc2 + residual(lat1)
    stage_rows_plain_bf16<16>(a.g1, Asb);
    gemm_stage<16>(Asb, a.s_fc2_W, a.s_fc2_b, a.lat2, a.lat1, 0, n);
    gsync(ctr, 4);
    // S5: gate (blocks 0..3)
    if (bid < NB) gate_stage(bid, a, ex);
    gsync(ctr, 5);
    // S6: LN(stateNew) -> paired K/V state rows
    stage_rows_ln_bf16<16>(a.stateNew, 0, 1, a.o_lnkv_g, a.o_lnkv_b, Asb, part1, part2);
    kv_cols_stage(Asb, a.o_Wk, a.o_bk, a.o_Wv, a.o_bv, a.kh2, a.vh2, n);
    gsync(ctr, 6);
    // S7: out-branch attention partials (last token)
    attn_part_stage<1>(a.q2h, a.kh2, a.vh2, a.pm, a.pl, a.pacc, smem);
    gsync(ctr, 7);
    // S8: combine + Wo + residual(lo_last)
    stage_combine<1>(a.pm, a.pl, a.pacc, Asb);
    gemm_stage<4>(Asb, a.o_Wo, a.o_bo, a.lo1, a.lo_last, 0, n);
    gsync(ctr, 8);
    // S9: LN + fc1 + gelu
    stage_rows_ln_bf16<4>(a.lo1, 0, 1, a.o_lnffn_g, a.o_lnffn_b, Asb, part1, part2);
    gemm_stage<4>(Asb, a.o_fc1_W, a.o_fc1_b, a.g2, nullptr, 1, n);
    gsync(ctr, 9);
    // S10: fc2 + residual(lo1)
    stage_rows_plain_bf16<4>(a.g2, Asb);
    gemm_stage<4>(Asb, a.o_fc2_W, a.o_fc2_b, a.lo2, a.lo1, 0, n);
    gsync(ctr, 10);
    // S11: output head -> y
    stage_rows_plain_bf16<4>(a.lo2, Asb);
    gemm_stage<4>(Asb, a.op_W, a.op_b, a.dout, nullptr, 0, n);
}

extern "C" void kernel_launch(void* const* d_in, const int* in_sizes, int n_in,
                              void* d_out, int out_size, void* d_ws, size_t ws_size,
                              hipStream_t stream)
{
    const float* x        = (const float*)d_in[0];
    const float* state0   = (const float*)d_in[1];
    const float* se_W     = (const float*)d_in[2];
    const float* se_b     = (const float*)d_in[3];
    const float* s_Wq     = (const float*)d_in[4];
    const float* s_bq     = (const float*)d_in[5];
    const float* s_Wk     = (const float*)d_in[6];
    const float* s_bk     = (const float*)d_in[7];
    const float* s_Wv     = (const float*)d_in[8];
    const float* s_bv     = (const float*)d_in[9];
    const float* s_Wo     = (const float*)d_in[10];
    const float* s_bo     = (const float*)d_in[11];
    const float* s_lnq_g  = (const float*)d_in[12];
    const float* s_lnq_b  = (const float*)d_in[13];
    const float* s_lnkv_g = (const float*)d_in[14];
    const float* s_lnkv_b = (const float*)d_in[15];
    const float* s_fc1_W  = (const float*)d_in[16];
    const float* s_fc1_b  = (const float*)d_in[17];
    const float* s_fc2_W  = (const float*)d_in[18];
    const float* s_fc2_b  = (const float*)d_in[19];
    const float* s_lnffn_g= (const float*)d_in[20];
    const float* s_lnffn_b= (const float*)d_in[21];
    const float* s_lnslot_g=(const float*)d_in[22];
    const float* s_lnslot_b=(const float*)d_in[23];
    const float* slot_ctx = (const float*)d_in[24];
    const float* oe_W     = (const float*)d_in[25];
    const float* oe_b     = (const float*)d_in[26];
    const float* o_Wq     = (const float*)d_in[27];
    const float* o_bq     = (const float*)d_in[28];
    const float* o_Wk     = (const float*)d_in[29];
    const float* o_bk     = (const float*)d_in[30];
    const float* o_Wv     = (const float*)d_in[31];
    const float* o_bv     = (const float*)d_in[32];
    const float* o_Wo     = (const float*)d_in[33];
    const float* o_bo     = (const float*)d_in[34];
    const float* o_lnq_g  = (const float*)d_in[35];
    const float* o_lnq_b  = (const float*)d_in[36];
    const float* o_lnkv_g = (const float*)d_in[37];
    const float* o_lnkv_b = (const float*)d_in[38];
    const float* o_fc1_W  = (const float*)d_in[39];
    const float* o_fc1_b  = (const float*)d_in[40];
    const float* o_fc2_W  = (const float*)d_in[41];
    const float* o_fc2_b  = (const float*)d_in[42];
    const float* o_lnffn_g= (const float*)d_in[43];
    const float* o_lnffn_b= (const float*)d_in[44];
    const float* op_W     = (const float*)d_in[45];
    const float* op_b     = (const float*)d_in[46];

    float* ws = (float*)d_ws;
    float* pe   = ws;
    float* cat  = ws + 1048576;
    bf16*  kh2  = (bf16*)(ws + 1048576);
    bf16*  vh2  = (bf16*)(ws + 1048576 + 2105344);
    bf16*  lnbb = (bf16*)(ws + 5259264);
    float* cat2 = ws + 7421952;
    bf16*  kh   = (bf16*)(ws + 7421952);
    bf16*  vh   = (bf16*)(ws + 7421952 + 2105344);
    bf16*  xb   = (bf16*)(ws + 11632640);
    bf16*  lnbb2= (bf16*)(ws + 11632640);
    bf16*  wb   = (bf16*)(ws + 13729792);
    bf16*  seWb = wb;
    bf16*  oeWb = wb + 1048576;
    bf16*  sWkb = wb + 2097152;
    bf16*  sWvb = wb + 3145728;
    bf16*  oWkb = wb + 4194304;
    bf16*  oWvb = wb + 5242880;
    float* sm   = ws + 16875520;
    float* qh_s    = sm + 16384;
    float* attn_s  = sm + 32768;   (void)attn_s;
    float* lat1    = sm + 49152;
    float* g1      = sm + 81920;
    float* lat2    = sm + 98304;
    float* q2h     = sm + 135232;
    float* lo_last = sm + 143424;
    float* lo1     = sm + 147520;
    float* g2      = sm + 155712;
    float* lo2     = sm + 159808;
    float* pmb     = sm + 163904;
    float* plb     = sm + 164928;
    float* paccb   = sm + 165952;
    float* stateNew= sm + 231488;
    int*   ctr     = (int*)(sm + 262144);
    float* out = (float*)d_out;

    dim3 blk(256);

    // ---- phase 0: conversions + PE + state-row copy + barrier reset ----
    PrepArgs pa;
    pa.cin[0] = x;    pa.cout[0] = xb;
    pa.cin[1] = se_W; pa.cout[1] = seWb;
    pa.cin[2] = oe_W; pa.cout[2] = oeWb;
    pa.cin[3] = s_Wk; pa.cout[3] = sWkb;
    pa.cin[4] = s_Wv; pa.cout[4] = sWvb;
    pa.cin[5] = o_Wk; pa.cout[5] = oWkb;
    pa.cin[6] = o_Wv; pa.cout[6] = oWvb;
    pa.state0 = state0; pa.cat = cat; pa.pe = pe; pa.ctr = ctr;
    prep_kernel<<<11281, blk, 0, stream>>>(pa);

    // ---- phase 1: both embeds, XCD-swizzled ----
    embed_fused_kernel<<<512, blk, 0, stream>>>(
        xb, seWb, oeWb, se_b, oe_b, cat, cat2, pe);

    // ---- phase 2: big LNs + q2/lo_last extraction (cat2 consumed before kv) ----
    ln_fused_kernel<<<8208, blk, 0, stream>>>(cat, cat2, lnbb, lnbb2,
        s_lnkv_g, s_lnkv_b, o_lnkv_g, o_lnkv_b);
    small_ln_gemm_kernel<4><<<256, blk, 0, stream>>>(cat2, TT - 1, LKV,
        o_lnq_g, o_lnq_b, o_Wq, o_bq, q2h);
    copy_lolast_kernel<<<NB, blk, 0, stream>>>(cat2, lo_last);

    // ---- phase 3: all four K/V GEMMs, XCD-swizzled. Overwrites cat/cat2. ----
    kv_fused_kernel<<<1056, blk, 0, stream>>>(
        lnbb, lnbb2, sWkb, sWvb, oWkb, oWvb,
        s_bk, s_bv, o_bk, o_bv, kh, vh, kh2, vh2);

    // ---- phase 4: persistent mega kernel (attn -> gate -> out-branch -> head) ----
    MegaArgs ma;
    ma.state0 = state0; ma.s_lnq_g = s_lnq_g; ma.s_lnq_b = s_lnq_b;
    ma.s_Wq = s_Wq; ma.s_bq = s_bq; ma.qh_s = qh_s;
    ma.kh = kh; ma.vh = vh; ma.pm = pmb; ma.pl = plb; ma.pacc = paccb;
    ma.s_Wo = s_Wo; ma.s_bo = s_bo; ma.lat1 = lat1;
    ma.s_lnffn_g = s_lnffn_g; ma.s_lnffn_b = s_lnffn_b;
    ma.s_fc1_W = s_fc1_W; ma.s_fc1_b = s_fc1_b; ma.g1 = g1;
    ma.s_fc2_W = s_fc2_W; ma.s_fc2_b = s_fc2_b; ma.lat2 = lat2;
    ma.s_lnslot_g = s_lnslot_g; ma.s_lnslot_b = s_lnslot_b; ma.slot_ctx = slot_ctx;
    ma.stateNew = stateNew;
    ma.o_lnkv_g = o_lnkv_g; ma.o_lnkv_b = o_lnkv_b;
    ma.o_Wk = o_Wk; ma.o_bk = o_bk; ma.o_Wv = o_Wv; ma.o_bv = o_bv;
    ma.kh2 = kh2; ma.vh2 = vh2; ma.q2h = q2h;
    ma.o_Wo = o_Wo; ma.o_bo = o_bo; ma.lo_last = lo_last; ma.lo1 = lo1;
    ma.o_lnffn_g = o_lnffn_g; ma.o_lnffn_b = o_lnffn_b;
    ma.o_fc1_W = o_fc1_W; ma.o_fc1_b = o_fc1_b; ma.g2 = g2;
    ma.o_fc2_W = o_fc2_W; ma.o_fc2_b = o_fc2_b; ma.lo2 = lo2;
    ma.op_W = op_W; ma.op_b = op_b; ma.dout = out; ma.ctr = ctr;
    mega_kernel<<<GRID_N, blk, 0, stream>>>(ma);
}

// Round 9
// 433.346 us; speedup vs baseline: 1.2566x; 1.2566x over previous
//
#include <hip/hip_runtime.h>
#include <hip/hip_bf16.h>

#define DD 1024
#define NB 4
#define TT 1024
#define NH 16
#define NS 4
#define LKV 1028   // NS + TT
#define NCH 4
#define CHS 257    // keys per chunk (4*257 = 1028)
#define GRID_N 256

typedef __hip_bfloat16 bf16;
typedef __attribute__((ext_vector_type(8))) short short8;
typedef __attribute__((ext_vector_type(4))) float f32x4;

#define GLD16(gp, lp) __builtin_amdgcn_global_load_lds( \
    (const __attribute__((address_space(1))) unsigned int*)(const void*)(gp), \
    (__attribute__((address_space(3))) unsigned int*)(void*)(lp), 16, 0, 0)

__device__ __forceinline__ float warp_sum(float v) {
#pragma unroll
    for (int o = 32; o > 0; o >>= 1) v += __shfl_xor(v, o);
    return v;
}

__device__ __forceinline__ float b2f(unsigned short u) {
    union { unsigned int i; float f; } x; x.i = ((unsigned)u) << 16; return x.f;
}
__device__ __forceinline__ unsigned short f2b(float f) {
    bf16 h = __float2bfloat16(f);
    union { bf16 h; unsigned short u; } x; x.h = h; return x.u;
}

// ================= prep: cvt x + 6 weights, PE table, state copy, ctr zero ====
struct PrepArgs {
    const float* cin[7];   // x, seW, oeW, sWk, sWv, oWk, oWv
    bf16* cout[7];
    const float* state0;
    float* cat;
    float* pe;
    int* ctr;
};

__global__ __launch_bounds__(256) void prep_kernel(PrepArgs a) {
    int bid = blockIdx.x;
    int tid = threadIdx.x;
    if (bid < 10240) {
        const float* in; bf16* out; size_t off;
        if (bid < 4096) { in = a.cin[0]; out = a.cout[0]; off = (size_t)bid * 1024; }
        else {
            int w = (bid - 4096) >> 10;
            in = a.cin[1 + w]; out = a.cout[1 + w];
            off = (size_t)((bid - 4096) & 1023) * 1024;
        }
        size_t i = off + tid * 4;
        float4 v = *(const float4*)(in + i);
        out[i + 0] = __float2bfloat16(v.x);
        out[i + 1] = __float2bfloat16(v.y);
        out[i + 2] = __float2bfloat16(v.z);
        out[i + 3] = __float2bfloat16(v.w);
    } else if (bid < 11264) {
        int t = bid - 10240;
#pragma unroll
        for (int i = 0; i < 2; ++i) {
            int j = i * 256 + tid;                       // 0..511
            float ang = (float)t * exp2f(-(float)j * (1.0f / 256.0f));
            a.pe[(size_t)t * DD + j]       = sinf(ang);
            a.pe[(size_t)t * DD + 512 + j] = cosf(ang);
        }
    } else if (bid < 11280) {
        int r = bid - 11264;       // 0..15
        int b = r >> 2, s = r & 3;
#pragma unroll
        for (int i = 0; i < 4; ++i)
            a.cat[(size_t)(b * LKV + s) * DD + i * 256 + tid] =
                a.state0[(size_t)r * DD + i * 256 + tid];
    } else {
        if (tid < 32) a.ctr[tid] = 0;   // grid-barrier counters
    }
}

// ================= fused LayerNorm -> bf16 (state-kv rows + out token rows) ===
__global__ __launch_bounds__(256) void ln_fused_kernel(
    const float* __restrict__ cat, const float* __restrict__ cat2,
    bf16* __restrict__ lnbb, bf16* __restrict__ lnbb2,
    const float* __restrict__ sg, const float* __restrict__ sb,
    const float* __restrict__ og, const float* __restrict__ ob)
{
    int bid = blockIdx.x;
    int tid = threadIdx.x;
    const float* in; bf16* out; const float* g; const float* b;
    if (bid < 4112) {
        in = cat + (size_t)bid * DD; out = lnbb + (size_t)bid * DD; g = sg; b = sb;
    } else {
        int r = bid - 4112;
        int row = (r >> 10) * LKV + (r & 1023);
        in = cat2 + (size_t)row * DD; out = lnbb2 + (size_t)r * DD; g = og; b = ob;
    }
    float v[4];
    float s1 = 0.f, s2 = 0.f;
#pragma unroll
    for (int i = 0; i < 4; ++i) {
        v[i] = in[i * 256 + tid];
        s1 += v[i]; s2 += v[i] * v[i];
    }
    s1 = warp_sum(s1); s2 = warp_sum(s2);
    __shared__ float a1[4], a2[4];
    int w = tid >> 6;
    if ((tid & 63) == 0) { a1[w] = s1; a2[w] = s2; }
    __syncthreads();
    s1 = a1[0] + a1[1] + a1[2] + a1[3];
    s2 = a2[0] + a2[1] + a2[2] + a2[3];
    float mu  = s1 * (1.0f / DD);
    float var = s2 * (1.0f / DD) - mu * mu;
    var = var < 0.f ? 0.f : var;
    float rs = rsqrtf(var + 1e-5f);
#pragma unroll
    for (int i = 0; i < 4; ++i) {
        int c = i * 256 + tid;
        out[c] = __float2bfloat16((v[i] - mu) * rs * g[c] + b[c]);
    }
}

// ================= MFMA tile body (128x128, BK=32, 4 waves) ===================
__device__ __forceinline__ void mfma_tile(
    const bf16* __restrict__ A, const bf16* __restrict__ W,
    const float* __restrict__ bias,
    float* __restrict__ outf, bf16* __restrict__ outb,
    int M, int obs, int oro, const float* __restrict__ pe,
    bf16* As, bf16* Ws, int m0, int n0)
{
    int tid  = threadIdx.x;
    int lane = tid & 63;
    int wave = tid >> 6;
    int wm = (wave >> 1) << 6;
    int wn = (wave & 1) << 6;

    f32x4 acc[4][4] = {};

    int soff  = wave * 1024 + lane * 16;
    int srow  = soff >> 6;
    int scol  = (soff & 63) >> 1;
    char* lA0 = (char*)As + wave * 1024;
    char* lA1 = (char*)As + 4096 + wave * 1024;
    char* lW0 = (char*)Ws + wave * 1024;
    char* lW1 = (char*)Ws + 4096 + wave * 1024;

    int fRow = lane & 15;
    int kOff = (lane >> 4) << 3;

    for (int k0 = 0; k0 < DD; k0 += 32) {
        GLD16(A + (size_t)(m0 + srow) * DD + k0 + scol,      lA0);
        GLD16(A + (size_t)(m0 + 64 + srow) * DD + k0 + scol, lA1);
        GLD16(W + (size_t)(n0 + srow) * DD + k0 + scol,      lW0);
        GLD16(W + (size_t)(n0 + 64 + srow) * DD + k0 + scol, lW1);
        __syncthreads();
        short8 a[4], b[4];
#pragma unroll
        for (int mi = 0; mi < 4; ++mi)
            a[mi] = *(const short8*)(As + (wm + mi * 16 + fRow) * 32 + kOff);
#pragma unroll
        for (int ni = 0; ni < 4; ++ni)
            b[ni] = *(const short8*)(Ws + (wn + ni * 16 + fRow) * 32 + kOff);
#pragma unroll
        for (int mi = 0; mi < 4; ++mi)
#pragma unroll
            for (int ni = 0; ni < 4; ++ni)
                acc[mi][ni] = __builtin_amdgcn_mfma_f32_16x16x32_bf16(
                    a[mi], b[ni], acc[mi][ni], 0, 0, 0);
        __syncthreads();
    }

    int cCol  = lane & 15;
    int cRow4 = (lane >> 4) << 2;
#pragma unroll
    for (int mi = 0; mi < 4; ++mi) {
#pragma unroll
        for (int ni = 0; ni < 4; ++ni) {
#pragma unroll
            for (int r = 0; r < 4; ++r) {
                int row = m0 + wm + mi * 16 + cRow4 + r;
                int col = n0 + wn + ni * 16 + cCol;
                if (row < M) {
                    float v = acc[mi][ni][r] + bias[col];
                    if (outf) {
                        v += pe[(size_t)(row & 1023) * DD + col];
                        int orow = (row >> 10) * obs + oro + (row & 1023);
                        outf[(size_t)orow * DD + col] = v;
                    } else {
                        int orow = obs ? ((row >> 10) * obs + (row & 1023)) : row;
                        outb[(size_t)orow * DD + col] = __float2bfloat16(v);
                    }
                }
            }
        }
    }
}

// ================= fused embeds, XCD-swizzled linear grid (512 blocks) ========
__global__ __launch_bounds__(256) void embed_fused_kernel(
    const bf16* __restrict__ xb,
    const bf16* __restrict__ seW, const bf16* __restrict__ oeW,
    const float* __restrict__ seb, const float* __restrict__ oeb,
    float* __restrict__ cat, float* __restrict__ cat2,
    const float* __restrict__ pe)
{
    __shared__ bf16 As[128 * 32];
    __shared__ bf16 Ws[128 * 32];
    int bid = blockIdx.x;
    int t = (bid & 7) * 64 + (bid >> 3);   // bijective XCD swizzle (512 = 8*64)
    int x = t & 7;
    int q = t >> 3;
    int z = q & 1;
    int y = q >> 1;
    const bf16* W = z ? oeW : seW;
    const float* bias = z ? oeb : seb;
    float* outf = z ? cat2 : cat;
    int oro = z ? 0 : NS;
    mfma_tile(xb, W, bias, outf, nullptr, 4096, LKV, oro, pe, As, Ws,
              y * 128, x * 128);
}

// ================= fused K/V GEMMs, XCD-swizzled linear grid (1056 blocks) ====
__global__ __launch_bounds__(256) void kv_fused_kernel(
    const bf16* __restrict__ lnbb, const bf16* __restrict__ lnbb2,
    const bf16* __restrict__ W0, const bf16* __restrict__ W1,
    const bf16* __restrict__ W2, const bf16* __restrict__ W3,
    const float* __restrict__ b0, const float* __restrict__ b1,
    const float* __restrict__ b2, const float* __restrict__ b3,
    bf16* __restrict__ o0, bf16* __restrict__ o1,
    bf16* __restrict__ o2, bf16* __restrict__ o3)
{
    __shared__ bf16 As[128 * 32];
    __shared__ bf16 Ws[128 * 32];
    int bid = blockIdx.x;
    int t = (bid & 7) * 132 + (bid >> 3);  // bijective XCD swizzle (1056 = 8*132)
    int x = t & 7;
    int u = t >> 3;          // 0..131
    int zi = u & 1;
    int v = u >> 1;          // 0..65
    int y = v % 33;
    int zp = v / 33;
    int z = zp * 2 + zi;
    const bf16* Warr[4] = {W0, W1, W2, W3};
    const float* barr[4] = {b0, b1, b2, b3};
    bf16* oarr[4] = {o0, o1, o2, o3};
    const bf16* A = (zp == 0) ? lnbb : lnbb2;
    int M   = (zp == 0) ? 4112 : 4096;
    int obs = (zp == 0) ? 0 : LKV;
    mfma_tile(A, Warr[z], barr[z], nullptr, oarr[z], M, obs, 0, nullptr, As, Ws,
              y * 128, x * 128);
}

// ============ small GEMM with fused input LayerNorm (standalone, q2 proj) =====
template<int M>
__global__ __launch_bounds__(256) void small_ln_gemm_kernel(
    const float* __restrict__ A, int row0, int rstride,
    const float* __restrict__ lng, const float* __restrict__ lnb,
    const float* __restrict__ W, const float* __restrict__ bias,
    float* __restrict__ outf)
{
    __shared__ float As[M * DD];
    __shared__ float smu[M], srs[M];
    int tid = threadIdx.x;
    int lane = tid & 63;
    int w = tid >> 6;
#pragma unroll
    for (int i = 0; i < M; ++i) {
        int row = row0 + i * rstride;
        *(float4*)(As + i * DD + tid * 4) =
            *(const float4*)(A + (size_t)row * DD + tid * 4);
    }
    __syncthreads();
    constexpr int RPW = (M + 3) / 4;
#pragma unroll
    for (int i = 0; i < RPW; ++i) {
        int r = w * RPW + i;
        if (r < M) {
            float s1 = 0.f, s2 = 0.f;
#pragma unroll
            for (int j = 0; j < 4; ++j) {
                float4 v = *(const float4*)(As + r * DD + (j * 64 + lane) * 4);
                s1 += v.x + v.y + v.z + v.w;
                s2 += v.x*v.x + v.y*v.y + v.z*v.z + v.w*v.w;
            }
            s1 = warp_sum(s1); s2 = warp_sum(s2);
            if (lane == 0) {
                float mu = s1 * (1.0f / DD);
                float var = s2 * (1.0f / DD) - mu * mu;
                var = var < 0.f ? 0.f : var;
                smu[r] = mu; srs[r] = rsqrtf(var + 1e-5f);
            }
        }
    }
    __syncthreads();
    float4 gv = *(const float4*)(lng + tid * 4);
    float4 bv = *(const float4*)(lnb + tid * 4);
#pragma unroll
    for (int i = 0; i < M; ++i) {
        float mu = smu[i], rs = srs[i];
        float4 v = *(const float4*)(As + i * DD + tid * 4);
        v.x = (v.x - mu) * rs * gv.x + bv.x;
        v.y = (v.y - mu) * rs * gv.y + bv.y;
        v.z = (v.z - mu) * rs * gv.z + bv.z;
        v.w = (v.w - mu) * rs * gv.w + bv.w;
        *(float4*)(As + i * DD + tid * 4) = v;
    }
    __syncthreads();
    int n = blockIdx.x * 4 + w;
    const float* Wr = W + (size_t)n * DD;
    float acc[M] = {};
#pragma unroll
    for (int j = 0; j < 4; ++j) {
        float4 wv = *(const float4*)(Wr + j * 256 + lane * 4);
#pragma unroll
        for (int m = 0; m < M; ++m) {
            float4 av = *(const float4*)(As + m * DD + j * 256 + lane * 4);
            acc[m] += av.x * wv.x + av.y * wv.y + av.z * wv.z + av.w * wv.w;
        }
    }
#pragma unroll
    for (int m = 0; m < M; ++m) acc[m] = warp_sum(acc[m]);
    if (lane == 0) {
#pragma unroll
        for (int m = 0; m < M; ++m)
            outf[(size_t)m * DD + n] = acc[m] + bias[n];
    }
}

// ================= copy lo[:, -1] =============================================
__global__ __launch_bounds__(256) void copy_lolast_kernel(
    const float* __restrict__ cat2, float* __restrict__ dst)
{
    int b = blockIdx.x;
    int tid = threadIdx.x;
#pragma unroll
    for (int i = 0; i < 4; ++i)
        dst[(size_t)b * DD + i * 256 + tid] =
            cat2[(size_t)(b * LKV + (TT - 1)) * DD + i * 256 + tid];
}

// ================= mega kernel: everything after kv_fused =====================
struct MegaArgs {
    const float *state0, *s_lnq_g, *s_lnq_b, *s_Wq, *s_bq;
    float *qh_s;
    const bf16 *kh, *vh;
    float *pm, *pl, *pacc;
    const float *s_Wo, *s_bo;
    float *lat1;
    const float *s_lnffn_g, *s_lnffn_b, *s_fc1_W, *s_fc1_b;
    float *g1;
    const float *s_fc2_W, *s_fc2_b;
    float *lat2;
    const float *s_lnslot_g, *s_lnslot_b, *slot_ctx;
    float *stateNew;
    const float *o_lnkv_g, *o_lnkv_b, *o_Wk, *o_bk, *o_Wv, *o_bv;
    bf16 *kh2, *vh2;
    const float *q2h;
    const float *o_Wo, *o_bo, *lo_last;
    float *lo1;
    const float *o_lnffn_g, *o_lnffn_b, *o_fc1_W, *o_fc1_b;
    float *g2;
    const float *o_fc2_W, *o_fc2_b;
    float *lo2;
    const float *op_W, *op_b;
    float *dout;
    int *ctr;
};

// Grid barrier: RELEASE arrive, RELAXED poll with s_sleep backoff, one ACQUIRE
// fence at exit. (Round-8's ACQUIRE-poll invalidated caches every iteration —
// ~35 us/barrier. RELAXED poll does no cache maintenance.)
__device__ __forceinline__ void gsync(int* ctr, int id) {
    __syncthreads();
    if (threadIdx.x == 0) {
        __hip_atomic_fetch_add(ctr + id, 1, __ATOMIC_RELEASE, __HIP_MEMORY_SCOPE_AGENT);
        long spins = 0;
        while (__hip_atomic_load(ctr + id, __ATOMIC_RELAXED, __HIP_MEMORY_SCOPE_AGENT)
                   < GRID_N && ++spins < (1L << 24))
            __builtin_amdgcn_s_sleep(2);
        __builtin_amdgcn_fence(__ATOMIC_ACQUIRE, "agent");
    }
    __syncthreads();
}

// stage M rows of A (row0 + i*rstride), LayerNorm them, store bf16 into Asb
template<int M>
__device__ void stage_rows_ln_bf16(
    const float* A, int row0, int rstride,
    const float* lng, const float* lnb,
    bf16* Asb, float* part1, float* part2)
{
    int tid = threadIdx.x, lane = tid & 63, w = tid >> 6;
#pragma unroll
    for (int i = 0; i < M; ++i) {
        const float* row = A + (size_t)(row0 + i * rstride) * DD;
        float4 v = *(const float4*)(row + tid * 4);
        float s1 = v.x + v.y + v.z + v.w;
        float s2 = v.x*v.x + v.y*v.y + v.z*v.z + v.w*v.w;
        s1 = warp_sum(s1); s2 = warp_sum(s2);
        if (lane == 0) { part1[i * 4 + w] = s1; part2[i * 4 + w] = s2; }
    }
    __syncthreads();
    float4 gv = *(const float4*)(lng + tid * 4);
    float4 bv = *(const float4*)(lnb + tid * 4);
#pragma unroll
    for (int i = 0; i < M; ++i) {
        float s1 = part1[i*4+0] + part1[i*4+1] + part1[i*4+2] + part1[i*4+3];
        float s2 = part2[i*4+0] + part2[i*4+1] + part2[i*4+2] + part2[i*4+3];
        float mu = s1 * (1.0f / DD);
        float var = s2 * (1.0f / DD) - mu * mu;
        var = var < 0.f ? 0.f : var;
        float rs = rsqrtf(var + 1e-5f);
        const float* row = A + (size_t)(row0 + i * rstride) * DD;
        float4 v = *(const float4*)(row + tid * 4);
        ushort4 o;
        o.x = f2b((v.x - mu) * rs * gv.x + bv.x);
        o.y = f2b((v.y - mu) * rs * gv.y + bv.y);
        o.z = f2b((v.z - mu) * rs * gv.z + bv.z);
        o.w = f2b((v.w - mu) * rs * gv.w + bv.w);
        *(ushort4*)(Asb + i * DD + tid * 4) = o;
    }
    __syncthreads();
}

template<int M>
__device__ void stage_rows_plain_bf16(const float* A, bf16* Asb)
{
    int tid = threadIdx.x;
#pragma unroll
    for (int i = 0; i < M; ++i) {
        float4 v = *(const float4*)(A + (size_t)i * DD + tid * 4);
        ushort4 o;
        o.x = f2b(v.x); o.y = f2b(v.y); o.z = f2b(v.z); o.w = f2b(v.w);
        *(ushort4*)(Asb + i * DD + tid * 4) = o;
    }
    __syncthreads();
}

// combine split-K attention partials directly into Asb (rows = b*LQ+qi)
template<int LQ>
__device__ void stage_combine(const float* pm, const float* pl,
                              const float* pacc, bf16* Asb)
{
    int tid = threadIdx.x;
    for (int idx = tid; idx < LQ * 4 * 256; idx += 256) {
        int m  = idx >> 8;
        int n4 = (idx & 255) * 4;
        int b = m / LQ, qi = m - b * LQ;
        int h = n4 >> 6, d = n4 & 63;
        int base = ((b * 16 + h) * 4 + qi) * NCH;
        float m0 = pm[base], m1 = pm[base+1], m2 = pm[base+2], m3 = pm[base+3];
        float Mx = fmaxf(fmaxf(m0, m1), fmaxf(m2, m3));
        float w0 = expf(m0-Mx), w1 = expf(m1-Mx), w2 = expf(m2-Mx), w3 = expf(m3-Mx);
        float L = pl[base]*w0 + pl[base+1]*w1 + pl[base+2]*w2 + pl[base+3]*w3;
        float inv = 1.f / L;
        float4 a0 = *(const float4*)(pacc + (size_t)(base+0)*64 + d);
        float4 a1 = *(const float4*)(pacc + (size_t)(base+1)*64 + d);
        float4 a2 = *(const float4*)(pacc + (size_t)(base+2)*64 + d);
        float4 a3 = *(const float4*)(pacc + (size_t)(base+3)*64 + d);
        ushort4 o;
        o.x = f2b((a0.x*w0 + a1.x*w1 + a2.x*w2 + a3.x*w3) * inv);
        o.y = f2b((a0.y*w0 + a1.y*w1 + a2.y*w2 + a3.y*w3) * inv);
        o.z = f2b((a0.z*w0 + a1.z*w1 + a2.z*w2 + a3.z*w3) * inv);
        o.w = f2b((a0.w*w0 + a1.w*w1 + a2.w*w2 + a3.w*w3) * inv);
        *(ushort4*)(Asb + m * DD + n4) = o;
    }
    __syncthreads();
}

// GEMM from bf16-staged A: out[m][n] = dot + bias (+gelu) (+res)
template<int M>
__device__ void gemm_stage(const bf16* Asb, const float* W, const float* bias,
                           float* outf, const float* res, int gelu, int n)
{
    int lane = threadIdx.x & 63;
    const float* Wr = W + (size_t)n * DD;
    float acc[M] = {};
#pragma unroll
    for (int j = 0; j < 4; ++j) {
        float4 wv = *(const float4*)(Wr + j * 256 + lane * 4);
#pragma unroll
        for (int m = 0; m < M; ++m) {
            ushort4 av = *(const ushort4*)(Asb + m * DD + j * 256 + lane * 4);
            acc[m] += b2f(av.x)*wv.x + b2f(av.y)*wv.y
                    + b2f(av.z)*wv.z + b2f(av.w)*wv.w;
        }
    }
#pragma unroll
    for (int m = 0; m < M; ++m) acc[m] = warp_sum(acc[m]);
    if (lane == 0) {
#pragma unroll
        for (int m = 0; m < M; ++m) {
            float v = acc[m] + bias[n];
            if (gelu) v = 0.5f * v * (1.0f + erff(v * 0.70710678118654752f));
            if (res)  v += res[(size_t)m * DD + n];
            outf[(size_t)m * DD + n] = v;
        }
    }
}

// paired K/V columns from LN'd state rows -> kh2/vh2 (remapped rows, bf16)
__device__ void kv_cols_stage(const bf16* Asb,
    const float* Wk, const float* bk, const float* Wv, const float* bv,
    bf16* kh2, bf16* vh2, int n)
{
    int lane = threadIdx.x & 63;
    const float* WrK = Wk + (size_t)n * DD;
    const float* WrV = Wv + (size_t)n * DD;
    float accK[16] = {}, accV[16] = {};
#pragma unroll
    for (int j = 0; j < 4; ++j) {
        float4 wk4 = *(const float4*)(WrK + j * 256 + lane * 4);
        float4 wv4 = *(const float4*)(WrV + j * 256 + lane * 4);
#pragma unroll
        for (int m = 0; m < 16; ++m) {
            ushort4 av = *(const ushort4*)(Asb + m * DD + j * 256 + lane * 4);
            float ax = b2f(av.x), ay = b2f(av.y), az = b2f(av.z), aw = b2f(av.w);
            accK[m] += ax*wk4.x + ay*wk4.y + az*wk4.z + aw*wk4.w;
            accV[m] += ax*wv4.x + ay*wv4.y + az*wv4.z + aw*wv4.w;
        }
    }
#pragma unroll
    for (int m = 0; m < 16; ++m) { accK[m] = warp_sum(accK[m]); accV[m] = warp_sum(accV[m]); }
    if (lane == 0) {
#pragma unroll
        for (int m = 0; m < 16; ++m) {
            int orow = (m >> 2) * LKV + TT + (m & 3);
            kh2[(size_t)orow * DD + n] = __float2bfloat16(accK[m] + bk[n]);
            vh2[(size_t)orow * DD + n] = __float2bfloat16(accV[m] + bv[n]);
        }
    }
}

// split-K attention partial (same mapping as round-7 kernel), smem overlay
template<int LQ>
__device__ void attn_part_stage(
    const float* qh, const bf16* kh, const bf16* vh,
    float* pm, float* pl, float* pacc, char* smem)
{
    float* qs    = (float*)smem;            // [4][64]
    float* sc    = qs + 4 * 64;             // [4][257]
    float* redm  = sc + 4 * 257;            // [4][4]
    float* redl  = redm + 16;               // [4][4]
    float* paccs = redl + 16;               // [4][4][64]
    int blk = blockIdx.x;
    int c  = blk & (NCH - 1);
    int bh = blk >> 2;
    int b = bh >> 4, h = bh & 15;
    int tid = threadIdx.x;
    int lane = tid & 63, w = tid >> 6;

    if (w < LQ) qs[w * 64 + lane] = qh[(size_t)(b * LQ + w) * DD + h * 64 + lane];
    __syncthreads();

    int kbeg = c * CHS;
    for (int t = tid; t < CHS; t += 256) {
        const ushort4* kr = (const ushort4*)((const unsigned short*)kh
            + (size_t)(b * LKV + kbeg + t) * DD + h * 64);
        float kf[64];
#pragma unroll
        for (int i = 0; i < 16; ++i) {
            ushort4 kk = kr[i];
            kf[i*4+0] = b2f(kk.x); kf[i*4+1] = b2f(kk.y);
            kf[i*4+2] = b2f(kk.z); kf[i*4+3] = b2f(kk.w);
        }
#pragma unroll
        for (int qi = 0; qi < LQ; ++qi) {
            float s = 0.f;
#pragma unroll
            for (int d = 0; d < 64; ++d) s += qs[qi * 64 + d] * kf[d];
            sc[qi * 257 + t] = s * 0.125f;
        }
    }
    __syncthreads();

    float M[LQ], L[LQ];
#pragma unroll
    for (int qi = 0; qi < LQ; ++qi) {
        float lm = -1e30f;
        for (int t = tid; t < CHS; t += 256) lm = fmaxf(lm, sc[qi * 257 + t]);
#pragma unroll
        for (int o = 32; o > 0; o >>= 1) lm = fmaxf(lm, __shfl_xor(lm, o));
        if (lane == 0) redm[w * 4 + qi] = lm;
    }
    __syncthreads();
#pragma unroll
    for (int qi = 0; qi < LQ; ++qi)
        M[qi] = fmaxf(fmaxf(redm[qi], redm[4 + qi]), fmaxf(redm[8 + qi], redm[12 + qi]));

#pragma unroll
    for (int qi = 0; qi < LQ; ++qi) {
        float ls = 0.f;
        for (int t = tid; t < CHS; t += 256) {
            float e = expf(sc[qi * 257 + t] - M[qi]);
            sc[qi * 257 + t] = e;
            ls += e;
        }
        ls = warp_sum(ls);
        if (lane == 0) redl[w * 4 + qi] = ls;
    }
    __syncthreads();
#pragma unroll
    for (int qi = 0; qi < LQ; ++qi)
        L[qi] = redl[qi] + redl[4 + qi] + redl[8 + qi] + redl[12 + qi];

    {
        int k0 = w * 65;
        int k1 = (k0 + 65 < CHS) ? k0 + 65 : CHS;
        float acc[LQ] = {};
        const unsigned short* vb = (const unsigned short*)vh
            + (size_t)(b * LKV + kbeg) * DD + h * 64 + lane;
        for (int k = k0; k < k1; ++k) {
            float v = b2f(vb[(size_t)k * DD]);
#pragma unroll
            for (int qi = 0; qi < LQ; ++qi) acc[qi] += sc[qi * 257 + k] * v;
        }
#pragma unroll
        for (int qi = 0; qi < LQ; ++qi) paccs[(w * 4 + qi) * 64 + lane] = acc[qi];
    }
    __syncthreads();
    if (tid < 64) {
#pragma unroll
        for (int qi = 0; qi < LQ; ++qi) {
            float s = paccs[qi * 64 + tid] + paccs[(4 + qi) * 64 + tid]
                    + paccs[(8 + qi) * 64 + tid] + paccs[(12 + qi) * 64 + tid];
            pacc[(size_t)((bh * 4 + qi) * NCH + c) * 64 + tid] = s;
        }
    }
    if (tid < LQ) {
        pm[(bh * 4 + tid) * NCH + c] = M[tid];
        pl[(bh * 4 + tid) * NCH + c] = L[tid];
    }
    __syncthreads();
}

__device__ void gate_stage(int b, const MegaArgs& a, float* ex)
{
    int tid = threadIdx.x, lane = tid & 63, w = tid >> 6;
    {
        const float* row = a.lat2 + (size_t)(b * NS + w) * DD;
        float4 v[4];
        float s1 = 0.f, s2 = 0.f;
#pragma unroll
        for (int j = 0; j < 4; ++j) {
            v[j] = *(const float4*)(row + (j * 64 + lane) * 4);
            s1 += v[j].x + v[j].y + v[j].z + v[j].w;
            s2 += v[j].x*v[j].x + v[j].y*v[j].y + v[j].z*v[j].z + v[j].w*v[j].w;
        }
        s1 = warp_sum(s1); s2 = warp_sum(s2);
        float mu = s1 * (1.0f / DD);
        float var = s2 * (1.0f / DD) - mu * mu;
        var = var < 0.f ? 0.f : var;
        float rs = rsqrtf(var + 1e-5f);
        float dot = 0.f;
#pragma unroll
        for (int j = 0; j < 4; ++j) {
            int c = (j * 64 + lane) * 4;
            float4 gv = *(const float4*)(a.s_lnslot_g + c);
            float4 bv = *(const float4*)(a.s_lnslot_b + c);
            float4 cv = *(const float4*)(a.slot_ctx + c);
            dot += ((v[j].x - mu) * rs * gv.x + bv.x) * cv.x
                 + ((v[j].y - mu) * rs * gv.y + bv.y) * cv.y
                 + ((v[j].z - mu) * rs * gv.z + bv.z) * cv.z
                 + ((v[j].w - mu) * rs * gv.w + bv.w) * cv.w;
        }
        dot = warp_sum(dot);
        if (lane == 0) ex[w] = dot;
    }
    __syncthreads();
    if (tid == 0) {
        float l[NS];
        for (int s = 0; s < NS; ++s) l[s] = ex[s];
        int i0 = 0;
        for (int s = 1; s < NS; ++s) if (l[s] > l[i0]) i0 = s;
        int i1 = (i0 == 0) ? 1 : 0;
        for (int s = 0; s < NS; ++s) if (s != i0 && l[s] > l[i1]) i1 = s;
        float mx = fmaxf(l[i0], l[i1]);
        float e0 = expf(l[i0] - mx), e1 = expf(l[i1] - mx);
        float inv = 1.f / (e0 + e1);
        for (int s = 0; s < NS; ++s) ex[4 + s] = 0.f;
        ex[4 + i0] = e0 * inv;
        ex[4 + i1] += e1 * inv;
        a.dout[4096 + b * 2 + 0] = (float)i0;
        a.dout[4096 + b * 2 + 1] = (float)i1;
    }
    __syncthreads();
    for (int idx = tid; idx < NS * DD; idx += 256) {
        int s = idx >> 10;
        float so = a.state0[(size_t)b * NS * DD + idx];
        float lt = a.lat2[(size_t)b * NS * DD + idx];
        float ns = 0.6f * so + 0.4f * ex[4 + s] * tanhf(lt);
        a.stateNew[(size_t)b * NS * DD + idx] = ns;
        a.dout[4104 + b * NS * DD + idx] = ns;
    }
}

__global__ __launch_bounds__(256) void mega_kernel(MegaArgs a)
{
    __shared__ char smem[33536];        // 32KB Asb + partials/extras
    bf16* Asb    = (bf16*)smem;         // [16][1024] bf16 = 32KB
    float* part1 = (float*)(smem + 32768);   // 64
    float* part2 = part1 + 64;               // 64
    float* ex    = part2 + 64;               // gate logits/alpha
    int* ctr = a.ctr;
    int bid = blockIdx.x;
    int w = threadIdx.x >> 6;
    int n = bid * 4 + w;

    // S0: qh_s = LN_q(state) @ sWq
    stage_rows_ln_bf16<16>(a.state0, 0, 1, a.s_lnq_g, a.s_lnq_b, Asb, part1, part2);
    gemm_stage<16>(Asb, a.s_Wq, a.s_bq, a.qh_s, nullptr, 0, n);
    gsync(ctr, 0);
    // S1: state-branch attention partials
    attn_part_stage<4>(a.qh_s, a.kh, a.vh, a.pm, a.pl, a.pacc, smem);
    gsync(ctr, 1);
    // S2: combine + Wo + residual(state)
    stage_combine<4>(a.pm, a.pl, a.pacc, Asb);
    gemm_stage<16>(Asb, a.s_Wo, a.s_bo, a.lat1, a.state0, 0, n);
    gsync(ctr, 2);
    // S3: LN + fc1 + gelu
    stage_rows_ln_bf16<16>(a.lat1, 0, 1, a.s_lnffn_g, a.s_lnffn_b, Asb, part1, part2);
    gemm_stage<16>(Asb, a.s_fc1_W, a.s_fc1_b, a.g1, nullptr, 1, n);
    gsync(ctr, 3);
    // S4: fc2 + residual(lat1)
    stage_rows_plain_bf16<16>(a.g1, Asb);
    gemm_stage<16>(Asb, a.s_fc2_W, a.s_fc2_b, a.lat2, a.lat1, 0, n);
    gsync(ctr, 4);
    // S5: gate (blocks 0..3)
    if (bid < NB) gate_stage(bid, a, ex);
    gsync(ctr, 5);
    // S6: LN(stateNew) -> paired K/V state rows
    stage_rows_ln_bf16<16>(a.stateNew, 0, 1, a.o_lnkv_g, a.o_lnkv_b, Asb, part1, part2);
    kv_cols_stage(Asb, a.o_Wk, a.o_bk, a.o_Wv, a.o_bv, a.kh2, a.vh2, n);
    gsync(ctr, 6);
    // S7: out-branch attention partials (last token)
    attn_part_stage<1>(a.q2h, a.kh2, a.vh2, a.pm, a.pl, a.pacc, smem);
    gsync(ctr, 7);
    // S8: combine + Wo + residual(lo_last)
    stage_combine<1>(a.pm, a.pl, a.pacc, Asb);
    gemm_stage<4>(Asb, a.o_Wo, a.o_bo, a.lo1, a.lo_last, 0, n);
    gsync(ctr, 8);
    // S9: LN + fc1 + gelu
    stage_rows_ln_bf16<4>(a.lo1, 0, 1, a.o_lnffn_g, a.o_lnffn_b, Asb, part1, part2);
    gemm_stage<4>(Asb, a.o_fc1_W, a.o_fc1_b, a.g2, nullptr, 1, n);
    gsync(ctr, 9);
    // S10: fc2 + residual(lo1)
    stage_rows_plain_bf16<4>(a.g2, Asb);
    gemm_stage<4>(Asb, a.o_fc2_W, a.o_fc2_b, a.lo2, a.lo1, 0, n);
    gsync(ctr, 10);
    // S11: output head -> y
    stage_rows_plain_bf16<4>(a.lo2, Asb);
    gemm_stage<4>(Asb, a.op_W, a.op_b, a.dout, nullptr, 0, n);
}

extern "C" void kernel_launch(void* const* d_in, const int* in_sizes, int n_in,
                              void* d_out, int out_size, void* d_ws, size_t ws_size,
                              hipStream_t stream)
{
    const float* x        = (const float*)d_in[0];
    const float* state0   = (const float*)d_in[1];
    const float* se_W     = (const float*)d_in[2];
    const float* se_b     = (const float*)d_in[3];
    const float* s_Wq     = (const float*)d_in[4];
    const float* s_bq     = (const float*)d_in[5];
    const float* s_Wk     = (const float*)d_in[6];
    const float* s_bk     = (const float*)d_in[7];
    const float* s_Wv     = (const float*)d_in[8];
    const float* s_bv     = (const float*)d_in[9];
    const float* s_Wo     = (const float*)d_in[10];
    const float* s_bo     = (const float*)d_in[11];
    const float* s_lnq_g  = (const float*)d_in[12];
    const float* s_lnq_b  = (const float*)d_in[13];
    const float* s_lnkv_g = (const float*)d_in[14];
    const float* s_lnkv_b = (const float*)d_in[15];
    const float* s_fc1_W  = (const float*)d_in[16];
    const float* s_fc1_b  = (const float*)d_in[17];
    const float* s_fc2_W  = (const float*)d_in[18];
    const float* s_fc2_b  = (const float*)d_in[19];
    const float* s_lnffn_g= (const float*)d_in[20];
    const float* s_lnffn_b= (const float*)d_in[21];
    const float* s_lnslot_g=(const float*)d_in[22];
    const float* s_lnslot_b=(const float*)d_in[23];
    const float* slot_ctx = (const float*)d_in[24];
    const float* oe_W     = (const float*)d_in[25];
    const float* oe_b     = (const float*)d_in[26];
    const float* o_Wq     = (const float*)d_in[27];
    const float* o_bq     = (const float*)d_in[28];
    const float* o_Wk     = (const float*)d_in[29];
    const float* o_bk     = (const float*)d_in[30];
    const float* o_Wv     = (const float*)d_in[31];
    const float* o_bv     = (const float*)d_in[32];
    const float* o_Wo     = (const float*)d_in[33];
    const float* o_bo     = (const float*)d_in[34];
    const float* o_lnq_g  = (const float*)d_in[35];
    const float* o_lnq_b  = (const float*)d_in[36];
    const float* o_lnkv_g = (const float*)d_in[37];
    const float* o_lnkv_b = (const float*)d_in[38];
    const float* o_fc1_W  = (const float*)d_in[39];
    const float* o_fc1_b  = (const float*)d_in[40];
    const float* o_fc2_W  = (const float*)d_in[41];
    const float* o_fc2_b  = (const float*)d_in[42];
    const float* o_lnffn_g= (const float*)d_in[43];
    const float* o_lnffn_b= (const float*)d_in[44];
    const float* op_W     = (const float*)d_in[45];
    const float* op_b     = (const float*)d_in[46];

    float* ws = (float*)d_ws;
    float* pe   = ws;
    float* cat  = ws + 1048576;
    bf16*  kh2  = (bf16*)(ws + 1048576);
    bf16*  vh2  = (bf16*)(ws + 1048576 + 2105344);
    bf16*  lnbb = (bf16*)(ws + 5259264);
    float* cat2 = ws + 7421952;
    bf16*  kh   = (bf16*)(ws + 7421952);
    bf16*  vh   = (bf16*)(ws + 7421952 + 2105344);
    bf16*  xb   = (bf16*)(ws + 11632640);
    bf16*  lnbb2= (bf16*)(ws + 11632640);
    bf16*  wb   = (bf16*)(ws + 13729792);
    bf16*  seWb = wb;
    bf16*  oeWb = wb + 1048576;
    bf16*  sWkb = wb + 2097152;
    bf16*  sWvb = wb + 3145728;
    bf16*  oWkb = wb + 4194304;
    bf16*  oWvb = wb + 5242880;
    float* sm   = ws + 16875520;
    float* qh_s    = sm + 16384;
    float* lat1    = sm + 49152;
    float* g1      = sm + 81920;
    float* lat2    = sm + 98304;
    float* q2h     = sm + 135232;
    float* lo_last = sm + 143424;
    float* lo1     = sm + 147520;
    float* g2      = sm + 155712;
    float* lo2     = sm + 159808;
    float* pmb     = sm + 163904;
    float* plb     = sm + 164928;
    float* paccb   = sm + 165952;
    float* stateNew= sm + 231488;
    int*   ctr     = (int*)(sm + 262144);
    float* out = (float*)d_out;

    dim3 blk(256);

    // ---- phase 0: conversions + PE + state-row copy + barrier reset ----
    PrepArgs pa;
    pa.cin[0] = x;    pa.cout[0] = xb;
    pa.cin[1] = se_W; pa.cout[1] = seWb;
    pa.cin[2] = oe_W; pa.cout[2] = oeWb;
    pa.cin[3] = s_Wk; pa.cout[3] = sWkb;
    pa.cin[4] = s_Wv; pa.cout[4] = sWvb;
    pa.cin[5] = o_Wk; pa.cout[5] = oWkb;
    pa.cin[6] = o_Wv; pa.cout[6] = oWvb;
    pa.state0 = state0; pa.cat = cat; pa.pe = pe; pa.ctr = ctr;
    prep_kernel<<<11281, blk, 0, stream>>>(pa);

    // ---- phase 1: both embeds, XCD-swizzled ----
    embed_fused_kernel<<<512, blk, 0, stream>>>(
        xb, seWb, oeWb, se_b, oe_b, cat, cat2, pe);

    // ---- phase 2: big LNs + q2/lo_last extraction (cat2 consumed before kv) ----
    ln_fused_kernel<<<8208, blk, 0, stream>>>(cat, cat2, lnbb, lnbb2,
        s_lnkv_g, s_lnkv_b, o_lnkv_g, o_lnkv_b);
    small_ln_gemm_kernel<4><<<256, blk, 0, stream>>>(cat2, TT - 1, LKV,
        o_lnq_g, o_lnq_b, o_Wq, o_bq, q2h);
    copy_lolast_kernel<<<NB, blk, 0, stream>>>(cat2, lo_last);

    // ---- phase 3: all four K/V GEMMs, XCD-swizzled. Overwrites cat/cat2. ----
    kv_fused_kernel<<<1056, blk, 0, stream>>>(
        lnbb, lnbb2, sWkb, sWvb, oWkb, oWvb,
        s_bk, s_bv, o_bk, o_bv, kh, vh, kh2, vh2);

    // ---- phase 4: persistent mega kernel (attn -> gate -> out-branch -> head) ----
    MegaArgs ma;
    ma.state0 = state0; ma.s_lnq_g = s_lnq_g; ma.s_lnq_b = s_lnq_b;
    ma.s_Wq = s_Wq; ma.s_bq = s_bq; ma.qh_s = qh_s;
    ma.kh = kh; ma.vh = vh; ma.pm = pmb; ma.pl = plb; ma.pacc = paccb;
    ma.s_Wo = s_Wo; ma.s_bo = s_bo; ma.lat1 = lat1;
    ma.s_lnffn_g = s_lnffn_g; ma.s_lnffn_b = s_lnffn_b;
    ma.s_fc1_W = s_fc1_W; ma.s_fc1_b = s_fc1_b; ma.g1 = g1;
    ma.s_fc2_W = s_fc2_W; ma.s_fc2_b = s_fc2_b; ma.lat2 = lat2;
    ma.s_lnslot_g = s_lnslot_g; ma.s_lnslot_b = s_lnslot_b; ma.slot_ctx = slot_ctx;
    ma.stateNew = stateNew;
    ma.o_lnkv_g = o_lnkv_g; ma.o_lnkv_b = o_lnkv_b;
    ma.o_Wk = o_Wk; ma.o_bk = o_bk; ma.o_Wv = o_Wv; ma.o_bv = o_bv;
    ma.kh2 = kh2; ma.vh2 = vh2; ma.q2h = q2h;
    ma.o_Wo = o_Wo; ma.o_bo = o_bo; ma.lo_last = lo_last; ma.lo1 = lo1;
    ma.o_lnffn_g = o_lnffn_g; ma.o_lnffn_b = o_lnffn_b;
    ma.o_fc1_W = o_fc1_W; ma.o_fc1_b = o_fc1_b; ma.g2 = g2;
    ma.o_fc2_W = o_fc2_W; ma.o_fc2_b = o_fc2_b; ma.lo2 = lo2;
    ma.op_W = op_W; ma.op_b = op_b; ma.dout = out; ma.ctr = ctr;
    mega_kernel<<<GRID_N, blk, 0, stream>>>(ma);
}

// Round 10
// 365.885 us; speedup vs baseline: 1.4882x; 1.1844x over previous
//
#include <hip/hip_runtime.h>
#include <hip/hip_bf16.h>

#define DD 1024
#define NB 4
#define TT 1024
#define NH 16
#define NS 4
#define LKV 1028   // NS + TT
#define NCH 4
#define CHS 257    // keys per chunk (4*257 = 1028)
#define GRID_N 256
#define NSUBC 32   // distributed barrier sub-counters
#define BARSTRIDE 544  // ints per barrier: 32 counters x 16-int pad + flag pad

typedef __hip_bfloat16 bf16;
typedef __attribute__((ext_vector_type(8))) short short8;
typedef __attribute__((ext_vector_type(4))) float f32x4;

#define GLD16(gp, lp) __builtin_amdgcn_global_load_lds( \
    (const __attribute__((address_space(1))) unsigned int*)(const void*)(gp), \
    (__attribute__((address_space(3))) unsigned int*)(void*)(lp), 16, 0, 0)

__device__ __forceinline__ float warp_sum(float v) {
#pragma unroll
    for (int o = 32; o > 0; o >>= 1) v += __shfl_xor(v, o);
    return v;
}

__device__ __forceinline__ float b2f(unsigned short u) {
    union { unsigned int i; float f; } x; x.i = ((unsigned)u) << 16; return x.f;
}
__device__ __forceinline__ unsigned short f2b(float f) {
    bf16 h = __float2bfloat16(f);
    union { bf16 h; unsigned short u; } x; x.h = h; return x.u;
}

// ================= prep: cvt x + 6 weights, PE table, state copy, ctr zero ====
struct PrepArgs {
    const float* cin[7];   // x, seW, oeW, sWk, sWv, oWk, oWv
    bf16* cout[7];
    const float* state0;
    float* cat;
    float* pe;
    int* ctr;
};

__global__ __launch_bounds__(256) void prep_kernel(PrepArgs a) {
    int bid = blockIdx.x;
    int tid = threadIdx.x;
    if (bid < 10240) {
        const float* in; bf16* out; size_t off;
        if (bid < 4096) { in = a.cin[0]; out = a.cout[0]; off = (size_t)bid * 1024; }
        else {
            int w = (bid - 4096) >> 10;
            in = a.cin[1 + w]; out = a.cout[1 + w];
            off = (size_t)((bid - 4096) & 1023) * 1024;
        }
        size_t i = off + tid * 4;
        float4 v = *(const float4*)(in + i);
        out[i + 0] = __float2bfloat16(v.x);
        out[i + 1] = __float2bfloat16(v.y);
        out[i + 2] = __float2bfloat16(v.z);
        out[i + 3] = __float2bfloat16(v.w);
    } else if (bid < 11264) {
        int t = bid - 10240;
#pragma unroll
        for (int i = 0; i < 2; ++i) {
            int j = i * 256 + tid;                       // 0..511
            float ang = (float)t * exp2f(-(float)j * (1.0f / 256.0f));
            a.pe[(size_t)t * DD + j]       = sinf(ang);
            a.pe[(size_t)t * DD + 512 + j] = cosf(ang);
        }
    } else if (bid < 11280) {
        int r = bid - 11264;       // 0..15
        int b = r >> 2, s = r & 3;
#pragma unroll
        for (int i = 0; i < 4; ++i)
            a.cat[(size_t)(b * LKV + s) * DD + i * 256 + tid] =
                a.state0[(size_t)r * DD + i * 256 + tid];
    } else {
        for (int i = tid; i < 12 * BARSTRIDE; i += 256) a.ctr[i] = 0;
    }
}

// ================= fused LayerNorm -> bf16 (state-kv rows + out token rows) ===
__global__ __launch_bounds__(256) void ln_fused_kernel(
    const float* __restrict__ cat, const float* __restrict__ cat2,
    bf16* __restrict__ lnbb, bf16* __restrict__ lnbb2,
    const float* __restrict__ sg, const float* __restrict__ sb,
    const float* __restrict__ og, const float* __restrict__ ob)
{
    int bid = blockIdx.x;
    int tid = threadIdx.x;
    const float* in; bf16* out; const float* g; const float* b;
    if (bid < 4112) {
        in = cat + (size_t)bid * DD; out = lnbb + (size_t)bid * DD; g = sg; b = sb;
    } else {
        int r = bid - 4112;
        int row = (r >> 10) * LKV + (r & 1023);
        in = cat2 + (size_t)row * DD; out = lnbb2 + (size_t)r * DD; g = og; b = ob;
    }
    float v[4];
    float s1 = 0.f, s2 = 0.f;
#pragma unroll
    for (int i = 0; i < 4; ++i) {
        v[i] = in[i * 256 + tid];
        s1 += v[i]; s2 += v[i] * v[i];
    }
    s1 = warp_sum(s1); s2 = warp_sum(s2);
    __shared__ float a1[4], a2[4];
    int w = tid >> 6;
    if ((tid & 63) == 0) { a1[w] = s1; a2[w] = s2; }
    __syncthreads();
    s1 = a1[0] + a1[1] + a1[2] + a1[3];
    s2 = a2[0] + a2[1] + a2[2] + a2[3];
    float mu  = s1 * (1.0f / DD);
    float var = s2 * (1.0f / DD) - mu * mu;
    var = var < 0.f ? 0.f : var;
    float rs = rsqrtf(var + 1e-5f);
#pragma unroll
    for (int i = 0; i < 4; ++i) {
        int c = i * 256 + tid;
        out[c] = __float2bfloat16((v[i] - mu) * rs * g[c] + b[c]);
    }
}

// ================= MFMA tile body (128x128, BK=32, 4 waves) ===================
__device__ __forceinline__ void mfma_tile(
    const bf16* __restrict__ A, const bf16* __restrict__ W,
    const float* __restrict__ bias,
    float* __restrict__ outf, bf16* __restrict__ outb,
    int M, int obs, int oro, const float* __restrict__ pe,
    bf16* As, bf16* Ws, int m0, int n0)
{
    int tid  = threadIdx.x;
    int lane = tid & 63;
    int wave = tid >> 6;
    int wm = (wave >> 1) << 6;
    int wn = (wave & 1) << 6;

    f32x4 acc[4][4] = {};

    int soff  = wave * 1024 + lane * 16;
    int srow  = soff >> 6;
    int scol  = (soff & 63) >> 1;
    char* lA0 = (char*)As + wave * 1024;
    char* lA1 = (char*)As + 4096 + wave * 1024;
    char* lW0 = (char*)Ws + wave * 1024;
    char* lW1 = (char*)Ws + 4096 + wave * 1024;

    int fRow = lane & 15;
    int kOff = (lane >> 4) << 3;

    for (int k0 = 0; k0 < DD; k0 += 32) {
        GLD16(A + (size_t)(m0 + srow) * DD + k0 + scol,      lA0);
        GLD16(A + (size_t)(m0 + 64 + srow) * DD + k0 + scol, lA1);
        GLD16(W + (size_t)(n0 + srow) * DD + k0 + scol,      lW0);
        GLD16(W + (size_t)(n0 + 64 + srow) * DD + k0 + scol, lW1);
        __syncthreads();
        short8 a[4], b[4];
#pragma unroll
        for (int mi = 0; mi < 4; ++mi)
            a[mi] = *(const short8*)(As + (wm + mi * 16 + fRow) * 32 + kOff);
#pragma unroll
        for (int ni = 0; ni < 4; ++ni)
            b[ni] = *(const short8*)(Ws + (wn + ni * 16 + fRow) * 32 + kOff);
#pragma unroll
        for (int mi = 0; mi < 4; ++mi)
#pragma unroll
            for (int ni = 0; ni < 4; ++ni)
                acc[mi][ni] = __builtin_amdgcn_mfma_f32_16x16x32_bf16(
                    a[mi], b[ni], acc[mi][ni], 0, 0, 0);
        __syncthreads();
    }

    int cCol  = lane & 15;
    int cRow4 = (lane >> 4) << 2;
#pragma unroll
    for (int mi = 0; mi < 4; ++mi) {
#pragma unroll
        for (int ni = 0; ni < 4; ++ni) {
#pragma unroll
            for (int r = 0; r < 4; ++r) {
                int row = m0 + wm + mi * 16 + cRow4 + r;
                int col = n0 + wn + ni * 16 + cCol;
                if (row < M) {
                    float v = acc[mi][ni][r] + bias[col];
                    if (outf) {
                        v += pe[(size_t)(row & 1023) * DD + col];
                        int orow = (row >> 10) * obs + oro + (row & 1023);
                        outf[(size_t)orow * DD + col] = v;
                    } else {
                        int orow = obs ? ((row >> 10) * obs + (row & 1023)) : row;
                        outb[(size_t)orow * DD + col] = __float2bfloat16(v);
                    }
                }
            }
        }
    }
}

// ================= fused embeds, XCD-swizzled linear grid (512 blocks) ========
__global__ __launch_bounds__(256) void embed_fused_kernel(
    const bf16* __restrict__ xb,
    const bf16* __restrict__ seW, const bf16* __restrict__ oeW,
    const float* __restrict__ seb, const float* __restrict__ oeb,
    float* __restrict__ cat, float* __restrict__ cat2,
    const float* __restrict__ pe)
{
    __shared__ bf16 As[128 * 32];
    __shared__ bf16 Ws[128 * 32];
    int bid = blockIdx.x;
    int t = (bid & 7) * 64 + (bid >> 3);   // bijective XCD swizzle (512 = 8*64)
    int x = t & 7;
    int q = t >> 3;
    int z = q & 1;
    int y = q >> 1;
    const bf16* W = z ? oeW : seW;
    const float* bias = z ? oeb : seb;
    float* outf = z ? cat2 : cat;
    int oro = z ? 0 : NS;
    mfma_tile(xb, W, bias, outf, nullptr, 4096, LKV, oro, pe, As, Ws,
              y * 128, x * 128);
}

// ================= fused K/V GEMMs, XCD-swizzled linear grid (1056 blocks) ====
__global__ __launch_bounds__(256) void kv_fused_kernel(
    const bf16* __restrict__ lnbb, const bf16* __restrict__ lnbb2,
    const bf16* __restrict__ W0, const bf16* __restrict__ W1,
    const bf16* __restrict__ W2, const bf16* __restrict__ W3,
    const float* __restrict__ b0, const float* __restrict__ b1,
    const float* __restrict__ b2, const float* __restrict__ b3,
    bf16* __restrict__ o0, bf16* __restrict__ o1,
    bf16* __restrict__ o2, bf16* __restrict__ o3)
{
    __shared__ bf16 As[128 * 32];
    __shared__ bf16 Ws[128 * 32];
    int bid = blockIdx.x;
    int t = (bid & 7) * 132 + (bid >> 3);  // bijective XCD swizzle (1056 = 8*132)
    int x = t & 7;
    int u = t >> 3;          // 0..131
    int zi = u & 1;
    int v = u >> 1;          // 0..65
    int y = v % 33;
    int zp = v / 33;
    int z = zp * 2 + zi;
    const bf16* Warr[4] = {W0, W1, W2, W3};
    const float* barr[4] = {b0, b1, b2, b3};
    bf16* oarr[4] = {o0, o1, o2, o3};
    const bf16* A = (zp == 0) ? lnbb : lnbb2;
    int M   = (zp == 0) ? 4112 : 4096;
    int obs = (zp == 0) ? 0 : LKV;
    mfma_tile(A, Warr[z], barr[z], nullptr, oarr[z], M, obs, 0, nullptr, As, Ws,
              y * 128, x * 128);
}

// ============ small GEMM with fused input LayerNorm (standalone, q2 proj) =====
template<int M>
__global__ __launch_bounds__(256) void small_ln_gemm_kernel(
    const float* __restrict__ A, int row0, int rstride,
    const float* __restrict__ lng, const float* __restrict__ lnb,
    const float* __restrict__ W, const float* __restrict__ bias,
    float* __restrict__ outf)
{
    __shared__ float As[M * DD];
    __shared__ float smu[M], srs[M];
    int tid = threadIdx.x;
    int lane = tid & 63;
    int w = tid >> 6;
#pragma unroll
    for (int i = 0; i < M; ++i) {
        int row = row0 + i * rstride;
        *(float4*)(As + i * DD + tid * 4) =
            *(const float4*)(A + (size_t)row * DD + tid * 4);
    }
    __syncthreads();
    constexpr int RPW = (M + 3) / 4;
#pragma unroll
    for (int i = 0; i < RPW; ++i) {
        int r = w * RPW + i;
        if (r < M) {
            float s1 = 0.f, s2 = 0.f;
#pragma unroll
            for (int j = 0; j < 4; ++j) {
                float4 v = *(const float4*)(As + r * DD + (j * 64 + lane) * 4);
                s1 += v.x + v.y + v.z + v.w;
                s2 += v.x*v.x + v.y*v.y + v.z*v.z + v.w*v.w;
            }
            s1 = warp_sum(s1); s2 = warp_sum(s2);
            if (lane == 0) {
                float mu = s1 * (1.0f / DD);
                float var = s2 * (1.0f / DD) - mu * mu;
                var = var < 0.f ? 0.f : var;
                smu[r] = mu; srs[r] = rsqrtf(var + 1e-5f);
            }
        }
    }
    __syncthreads();
    float4 gv = *(const float4*)(lng + tid * 4);
    float4 bv = *(const float4*)(lnb + tid * 4);
#pragma unroll
    for (int i = 0; i < M; ++i) {
        float mu = smu[i], rs = srs[i];
        float4 v = *(const float4*)(As + i * DD + tid * 4);
        v.x = (v.x - mu) * rs * gv.x + bv.x;
        v.y = (v.y - mu) * rs * gv.y + bv.y;
        v.z = (v.z - mu) * rs * gv.z + bv.z;
        v.w = (v.w - mu) * rs * gv.w + bv.w;
        *(float4*)(As + i * DD + tid * 4) = v;
    }
    __syncthreads();
    int n = blockIdx.x * 4 + w;
    const float* Wr = W + (size_t)n * DD;
    float acc[M] = {};
#pragma unroll
    for (int j = 0; j < 4; ++j) {
        float4 wv = *(const float4*)(Wr + j * 256 + lane * 4);
#pragma unroll
        for (int m = 0; m < M; ++m) {
            float4 av = *(const float4*)(As + m * DD + j * 256 + lane * 4);
            acc[m] += av.x * wv.x + av.y * wv.y + av.z * wv.z + av.w * wv.w;
        }
    }
#pragma unroll
    for (int m = 0; m < M; ++m) acc[m] = warp_sum(acc[m]);
    if (lane == 0) {
#pragma unroll
        for (int m = 0; m < M; ++m)
            outf[(size_t)m * DD + n] = acc[m] + bias[n];
    }
}

// ================= copy lo[:, -1] =============================================
__global__ __launch_bounds__(256) void copy_lolast_kernel(
    const float* __restrict__ cat2, float* __restrict__ dst)
{
    int b = blockIdx.x;
    int tid = threadIdx.x;
#pragma unroll
    for (int i = 0; i < 4; ++i)
        dst[(size_t)b * DD + i * 256 + tid] =
            cat2[(size_t)(b * LKV + (TT - 1)) * DD + i * 256 + tid];
}

// ================= mega kernel: everything after kv_fused =====================
struct MegaArgs {
    const float *state0, *s_lnq_g, *s_lnq_b, *s_Wq, *s_bq;
    float *qh_s;
    const bf16 *kh, *vh;
    float *pm, *pl, *pacc;
    const float *s_Wo, *s_bo;
    float *lat1;
    const float *s_lnffn_g, *s_lnffn_b, *s_fc1_W, *s_fc1_b;
    float *g1;
    const float *s_fc2_W, *s_fc2_b;
    float *lat2;
    const float *s_lnslot_g, *s_lnslot_b, *slot_ctx;
    float *stateNew;
    const float *o_lnkv_g, *o_lnkv_b, *o_Wk, *o_bk, *o_Wv, *o_bv;
    bf16 *kh2, *vh2;
    const float *q2h;
    const float *o_Wo, *o_bo, *lo_last;
    float *lo1;
    const float *o_lnffn_g, *o_lnffn_b, *o_fc1_W, *o_fc1_b;
    float *g2;
    const float *o_fc2_W, *o_fc2_b;
    float *lo2;
    const float *op_W, *op_b;
    float *dout;
    int *ctr;
};

// Distributed grid barrier. Round-9's single-counter fetch_add serialized 256
// LLC RMWs on one line (~28 us/barrier). Here: arrive on one of 32 padded
// sub-counters (8 RMWs/line); block 0's wave-0 polls all 32 in parallel
// (RELAXED) and releases a broadcast flag; others poll the flag (read-only
// line, no ownership ping-pong). One acquire fence at exit.
__device__ __forceinline__ void gsync(int* base, int id) {
    __syncthreads();
    int* sub = base + id * BARSTRIDE;
    int tid = threadIdx.x;
    if (tid == 0)
        __hip_atomic_fetch_add(sub + (blockIdx.x & (NSUBC - 1)) * 16, 1,
                               __ATOMIC_RELEASE, __HIP_MEMORY_SCOPE_AGENT);
    if (blockIdx.x == 0) {
        if (tid < 64) {
            long spins = 0;
            while (spins < (1L << 22)) {
                int v = (tid < NSUBC)
                    ? __hip_atomic_load(sub + tid * 16, __ATOMIC_RELAXED,
                                        __HIP_MEMORY_SCOPE_AGENT)
                    : 0;
                int s = v;
#pragma unroll
                for (int o = 32; o > 0; o >>= 1) s += __shfl_xor(s, o);
                if (s >= GRID_N) break;
                __builtin_amdgcn_s_sleep(1);
                ++spins;
            }
            if (tid == 0) {
                __builtin_amdgcn_fence(__ATOMIC_ACQUIRE, "agent");
                __hip_atomic_store(sub + 512, 1, __ATOMIC_RELEASE,
                                   __HIP_MEMORY_SCOPE_AGENT);
            }
        }
    } else if (tid == 0) {
        long spins = 0;
        while (__hip_atomic_load(sub + 512, __ATOMIC_RELAXED,
                                 __HIP_MEMORY_SCOPE_AGENT) == 0
               && ++spins < (1L << 22))
            __builtin_amdgcn_s_sleep(1);
        __builtin_amdgcn_fence(__ATOMIC_ACQUIRE, "agent");
    }
    __syncthreads();
}

// stage M rows of A (row0 + i*rstride), LayerNorm them, store bf16 into Asb
template<int M>
__device__ void stage_rows_ln_bf16(
    const float* A, int row0, int rstride,
    const float* lng, const float* lnb,
    bf16* Asb, float* part1, float* part2)
{
    int tid = threadIdx.x, lane = tid & 63, w = tid >> 6;
#pragma unroll
    for (int i = 0; i < M; ++i) {
        const float* row = A + (size_t)(row0 + i * rstride) * DD;
        float4 v = *(const float4*)(row + tid * 4);
        float s1 = v.x + v.y + v.z + v.w;
        float s2 = v.x*v.x + v.y*v.y + v.z*v.z + v.w*v.w;
        s1 = warp_sum(s1); s2 = warp_sum(s2);
        if (lane == 0) { part1[i * 4 + w] = s1; part2[i * 4 + w] = s2; }
    }
    __syncthreads();
    float4 gv = *(const float4*)(lng + tid * 4);
    float4 bv = *(const float4*)(lnb + tid * 4);
#pragma unroll
    for (int i = 0; i < M; ++i) {
        float s1 = part1[i*4+0] + part1[i*4+1] + part1[i*4+2] + part1[i*4+3];
        float s2 = part2[i*4+0] + part2[i*4+1] + part2[i*4+2] + part2[i*4+3];
        float mu = s1 * (1.0f / DD);
        float var = s2 * (1.0f / DD) - mu * mu;
        var = var < 0.f ? 0.f : var;
        float rs = rsqrtf(var + 1e-5f);
        const float* row = A + (size_t)(row0 + i * rstride) * DD;
        float4 v = *(const float4*)(row + tid * 4);
        ushort4 o;
        o.x = f2b((v.x - mu) * rs * gv.x + bv.x);
        o.y = f2b((v.y - mu) * rs * gv.y + bv.y);
        o.z = f2b((v.z - mu) * rs * gv.z + bv.z);
        o.w = f2b((v.w - mu) * rs * gv.w + bv.w);
        *(ushort4*)(Asb + i * DD + tid * 4) = o;
    }
    __syncthreads();
}

template<int M>
__device__ void stage_rows_plain_bf16(const float* A, bf16* Asb)
{
    int tid = threadIdx.x;
#pragma unroll
    for (int i = 0; i < M; ++i) {
        float4 v = *(const float4*)(A + (size_t)i * DD + tid * 4);
        ushort4 o;
        o.x = f2b(v.x); o.y = f2b(v.y); o.z = f2b(v.z); o.w = f2b(v.w);
        *(ushort4*)(Asb + i * DD + tid * 4) = o;
    }
    __syncthreads();
}

// combine split-K attention partials directly into Asb (rows = b*LQ+qi)
template<int LQ>
__device__ void stage_combine(const float* pm, const float* pl,
                              const float* pacc, bf16* Asb)
{
    int tid = threadIdx.x;
    for (int idx = tid; idx < LQ * 4 * 256; idx += 256) {
        int m  = idx >> 8;
        int n4 = (idx & 255) * 4;
        int b = m / LQ, qi = m - b * LQ;
        int h = n4 >> 6, d = n4 & 63;
        int base = ((b * 16 + h) * 4 + qi) * NCH;
        float m0 = pm[base], m1 = pm[base+1], m2 = pm[base+2], m3 = pm[base+3];
        float Mx = fmaxf(fmaxf(m0, m1), fmaxf(m2, m3));
        float w0 = expf(m0-Mx), w1 = expf(m1-Mx), w2 = expf(m2-Mx), w3 = expf(m3-Mx);
        float L = pl[base]*w0 + pl[base+1]*w1 + pl[base+2]*w2 + pl[base+3]*w3;
        float inv = 1.f / L;
        float4 a0 = *(const float4*)(pacc + (size_t)(base+0)*64 + d);
        float4 a1 = *(const float4*)(pacc + (size_t)(base+1)*64 + d);
        float4 a2 = *(const float4*)(pacc + (size_t)(base+2)*64 + d);
        float4 a3 = *(const float4*)(pacc + (size_t)(base+3)*64 + d);
        ushort4 o;
        o.x = f2b((a0.x*w0 + a1.x*w1 + a2.x*w2 + a3.x*w3) * inv);
        o.y = f2b((a0.y*w0 + a1.y*w1 + a2.y*w2 + a3.y*w3) * inv);
        o.z = f2b((a0.z*w0 + a1.z*w1 + a2.z*w2 + a3.z*w3) * inv);
        o.w = f2b((a0.w*w0 + a1.w*w1 + a2.w*w2 + a3.w*w3) * inv);
        *(ushort4*)(Asb + m * DD + n4) = o;
    }
    __syncthreads();
}

// GEMM from bf16-staged A: out[m][n] = dot + bias (+gelu) (+res)
template<int M>
__device__ void gemm_stage(const bf16* Asb, const float* W, const float* bias,
                           float* outf, const float* res, int gelu, int n)
{
    int lane = threadIdx.x & 63;
    const float* Wr = W + (size_t)n * DD;
    float acc[M] = {};
#pragma unroll
    for (int j = 0; j < 4; ++j) {
        float4 wv = *(const float4*)(Wr + j * 256 + lane * 4);
#pragma unroll
        for (int m = 0; m < M; ++m) {
            ushort4 av = *(const ushort4*)(Asb + m * DD + j * 256 + lane * 4);
            acc[m] += b2f(av.x)*wv.x + b2f(av.y)*wv.y
                    + b2f(av.z)*wv.z + b2f(av.w)*wv.w;
        }
    }
#pragma unroll
    for (int m = 0; m < M; ++m) acc[m] = warp_sum(acc[m]);
    if (lane == 0) {
#pragma unroll
        for (int m = 0; m < M; ++m) {
            float v = acc[m] + bias[n];
            if (gelu) v = 0.5f * v * (1.0f + erff(v * 0.70710678118654752f));
            if (res)  v += res[(size_t)m * DD + n];
            outf[(size_t)m * DD + n] = v;
        }
    }
}

// paired K/V columns from LN'd state rows -> kh2/vh2 (remapped rows, bf16)
__device__ void kv_cols_stage(const bf16* Asb,
    const float* Wk, const float* bk, const float* Wv, const float* bv,
    bf16* kh2, bf16* vh2, int n)
{
    int lane = threadIdx.x & 63;
    const float* WrK = Wk + (size_t)n * DD;
    const float* WrV = Wv + (size_t)n * DD;
    float accK[16] = {}, accV[16] = {};
#pragma unroll
    for (int j = 0; j < 4; ++j) {
        float4 wk4 = *(const float4*)(WrK + j * 256 + lane * 4);
        float4 wv4 = *(const float4*)(WrV + j * 256 + lane * 4);
#pragma unroll
        for (int m = 0; m < 16; ++m) {
            ushort4 av = *(const ushort4*)(Asb + m * DD + j * 256 + lane * 4);
            float ax = b2f(av.x), ay = b2f(av.y), az = b2f(av.z), aw = b2f(av.w);
            accK[m] += ax*wk4.x + ay*wk4.y + az*wk4.z + aw*wk4.w;
            accV[m] += ax*wv4.x + ay*wv4.y + az*wv4.z + aw*wv4.w;
        }
    }
#pragma unroll
    for (int m = 0; m < 16; ++m) { accK[m] = warp_sum(accK[m]); accV[m] = warp_sum(accV[m]); }
    if (lane == 0) {
#pragma unroll
        for (int m = 0; m < 16; ++m) {
            int orow = (m >> 2) * LKV + TT + (m & 3);
            kh2[(size_t)orow * DD + n] = __float2bfloat16(accK[m] + bk[n]);
            vh2[(size_t)orow * DD + n] = __float2bfloat16(accV[m] + bv[n]);
        }
    }
}

// split-K attention partial (same mapping as round-7 kernel), smem overlay
template<int LQ>
__device__ void attn_part_stage(
    const float* qh, const bf16* kh, const bf16* vh,
    float* pm, float* pl, float* pacc, char* smem)
{
    float* qs    = (float*)smem;            // [4][64]
    float* sc    = qs + 4 * 64;             // [4][257]
    float* redm  = sc + 4 * 257;            // [4][4]
    float* redl  = redm + 16;               // [4][4]
    float* paccs = redl + 16;               // [4][4][64]
    int blk = blockIdx.x;
    int c  = blk & (NCH - 1);
    int bh = blk >> 2;
    int b = bh >> 4, h = bh & 15;
    int tid = threadIdx.x;
    int lane = tid & 63, w = tid >> 6;

    if (w < LQ) qs[w * 64 + lane] = qh[(size_t)(b * LQ + w) * DD + h * 64 + lane];
    __syncthreads();

    int kbeg = c * CHS;
    for (int t = tid; t < CHS; t += 256) {
        const ushort4* kr = (const ushort4*)((const unsigned short*)kh
            + (size_t)(b * LKV + kbeg + t) * DD + h * 64);
        float kf[64];
#pragma unroll
        for (int i = 0; i < 16; ++i) {
            ushort4 kk = kr[i];
            kf[i*4+0] = b2f(kk.x); kf[i*4+1] = b2f(kk.y);
            kf[i*4+2] = b2f(kk.z); kf[i*4+3] = b2f(kk.w);
        }
#pragma unroll
        for (int qi = 0; qi < LQ; ++qi) {
            float s = 0.f;
#pragma unroll
            for (int d = 0; d < 64; ++d) s += qs[qi * 64 + d] * kf[d];
            sc[qi * 257 + t] = s * 0.125f;
        }
    }
    __syncthreads();

    float M[LQ], L[LQ];
#pragma unroll
    for (int qi = 0; qi < LQ; ++qi) {
        float lm = -1e30f;
        for (int t = tid; t < CHS; t += 256) lm = fmaxf(lm, sc[qi * 257 + t]);
#pragma unroll
        for (int o = 32; o > 0; o >>= 1) lm = fmaxf(lm, __shfl_xor(lm, o));
        if (lane == 0) redm[w * 4 + qi] = lm;
    }
    __syncthreads();
#pragma unroll
    for (int qi = 0; qi < LQ; ++qi)
        M[qi] = fmaxf(fmaxf(redm[qi], redm[4 + qi]), fmaxf(redm[8 + qi], redm[12 + qi]));

#pragma unroll
    for (int qi = 0; qi < LQ; ++qi) {
        float ls = 0.f;
        for (int t = tid; t < CHS; t += 256) {
            float e = expf(sc[qi * 257 + t] - M[qi]);
            sc[qi * 257 + t] = e;
            ls += e;
        }
        ls = warp_sum(ls);
        if (lane == 0) redl[w * 4 + qi] = ls;
    }
    __syncthreads();
#pragma unroll
    for (int qi = 0; qi < LQ; ++qi)
        L[qi] = redl[qi] + redl[4 + qi] + redl[8 + qi] + redl[12 + qi];

    {
        int k0 = w * 65;
        int k1 = (k0 + 65 < CHS) ? k0 + 65 : CHS;
        float acc[LQ] = {};
        const unsigned short* vb = (const unsigned short*)vh
            + (size_t)(b * LKV + kbeg) * DD + h * 64 + lane;
        for (int k = k0; k < k1; ++k) {
            float v = b2f(vb[(size_t)k * DD]);
#pragma unroll
            for (int qi = 0; qi < LQ; ++qi) acc[qi] += sc[qi * 257 + k] * v;
        }
#pragma unroll
        for (int qi = 0; qi < LQ; ++qi) paccs[(w * 4 + qi) * 64 + lane] = acc[qi];
    }
    __syncthreads();
    if (tid < 64) {
#pragma unroll
        for (int qi = 0; qi < LQ; ++qi) {
            float s = paccs[qi * 64 + tid] + paccs[(4 + qi) * 64 + tid]
                    + paccs[(8 + qi) * 64 + tid] + paccs[(12 + qi) * 64 + tid];
            pacc[(size_t)((bh * 4 + qi) * NCH + c) * 64 + tid] = s;
        }
    }
    if (tid < LQ) {
        pm[(bh * 4 + tid) * NCH + c] = M[tid];
        pl[(bh * 4 + tid) * NCH + c] = L[tid];
    }
    __syncthreads();
}

__device__ void gate_stage(int b, const MegaArgs& a, float* ex)
{
    int tid = threadIdx.x, lane = tid & 63, w = tid >> 6;
    {
        const float* row = a.lat2 + (size_t)(b * NS + w) * DD;
        float4 v[4];
        float s1 = 0.f, s2 = 0.f;
#pragma unroll
        for (int j = 0; j < 4; ++j) {
            v[j] = *(const float4*)(row + (j * 64 + lane) * 4);
            s1 += v[j].x + v[j].y + v[j].z + v[j].w;
            s2 += v[j].x*v[j].x + v[j].y*v[j].y + v[j].z*v[j].z + v[j].w*v[j].w;
        }
        s1 = warp_sum(s1); s2 = warp_sum(s2);
        float mu = s1 * (1.0f / DD);
        float var = s2 * (1.0f / DD) - mu * mu;
        var = var < 0.f ? 0.f : var;
        float rs = rsqrtf(var + 1e-5f);
        float dot = 0.f;
#pragma unroll
        for (int j = 0; j < 4; ++j) {
            int c = (j * 64 + lane) * 4;
            float4 gv = *(const float4*)(a.s_lnslot_g + c);
            float4 bv = *(const float4*)(a.s_lnslot_b + c);
            float4 cv = *(const float4*)(a.slot_ctx + c);
            dot += ((v[j].x - mu) * rs * gv.x + bv.x) * cv.x
                 + ((v[j].y - mu) * rs * gv.y + bv.y) * cv.y
                 + ((v[j].z - mu) * rs * gv.z + bv.z) * cv.z
                 + ((v[j].w - mu) * rs * gv.w + bv.w) * cv.w;
        }
        dot = warp_sum(dot);
        if (lane == 0) ex[w] = dot;
    }
    __syncthreads();
    if (tid == 0) {
        float l[NS];
        for (int s = 0; s < NS; ++s) l[s] = ex[s];
        int i0 = 0;
        for (int s = 1; s < NS; ++s) if (l[s] > l[i0]) i0 = s;
        int i1 = (i0 == 0) ? 1 : 0;
        for (int s = 0; s < NS; ++s) if (s != i0 && l[s] > l[i1]) i1 = s;
        float mx = fmaxf(l[i0], l[i1]);
        float e0 = expf(l[i0] - mx), e1 = expf(l[i1] - mx);
        float inv = 1.f / (e0 + e1);
        for (int s = 0; s < NS; ++s) ex[4 + s] = 0.f;
        ex[4 + i0] = e0 * inv;
        ex[4 + i1] += e1 * inv;
        a.dout[4096 + b * 2 + 0] = (float)i0;
        a.dout[4096 + b * 2 + 1] = (float)i1;
    }
    __syncthreads();
    for (int idx = tid; idx < NS * DD; idx += 256) {
        int s = idx >> 10;
        float so = a.state0[(size_t)b * NS * DD + idx];
        float lt = a.lat2[(size_t)b * NS * DD + idx];
        float ns = 0.6f * so + 0.4f * ex[4 + s] * tanhf(lt);
        a.stateNew[(size_t)b * NS * DD + idx] = ns;
        a.dout[4104 + b * NS * DD + idx] = ns;
    }
}

__global__ __launch_bounds__(256) void mega_kernel(MegaArgs a)
{
    __shared__ char smem[33536];        // 32KB Asb + partials/extras
    bf16* Asb    = (bf16*)smem;         // [16][1024] bf16 = 32KB
    float* part1 = (float*)(smem + 32768);   // 64
    float* part2 = part1 + 64;               // 64
    float* ex    = part2 + 64;               // gate logits/alpha
    int* ctr = a.ctr;
    int bid = blockIdx.x;
    int w = threadIdx.x >> 6;
    int n = bid * 4 + w;

    // S0: qh_s = LN_q(state) @ sWq
    stage_rows_ln_bf16<16>(a.state0, 0, 1, a.s_lnq_g, a.s_lnq_b, Asb, part1, part2);
    gemm_stage<16>(Asb, a.s_Wq, a.s_bq, a.qh_s, nullptr, 0, n);
    gsync(ctr, 0);
    // S1: state-branch attention partials
    attn_part_stage<4>(a.qh_s, a.kh, a.vh, a.pm, a.pl, a.pacc, smem);
    gsync(ctr, 1);
    // S2: combine + Wo + residual(state)
    stage_combine<4>(a.pm, a.pl, a.pacc, Asb);
    gemm_stage<16>(Asb, a.s_Wo, a.s_bo, a.lat1, a.state0, 0, n);
    gsync(ctr, 2);
    // S3: LN + fc1 + gelu
    stage_rows_ln_bf16<16>(a.lat1, 0, 1, a.s_lnffn_g, a.s_lnffn_b, Asb, part1, part2);
    gemm_stage<16>(Asb, a.s_fc1_W, a.s_fc1_b, a.g1, nullptr, 1, n);
    gsync(ctr, 3);
    // S4: fc2 + residual(lat1)
    stage_rows_plain_bf16<16>(a.g1, Asb);
    gemm_stage<16>(Asb, a.s_fc2_W, a.s_fc2_b, a.lat2, a.lat1, 0, n);
    gsync(ctr, 4);
    // S5: gate (blocks 0..3)
    if (bid < NB) gate_stage(bid, a, ex);
    gsync(ctr, 5);
    // S6: LN(stateNew) -> paired K/V state rows
    stage_rows_ln_bf16<16>(a.stateNew, 0, 1, a.o_lnkv_g, a.o_lnkv_b, Asb, part1, part2);
    kv_cols_stage(Asb, a.o_Wk, a.o_bk, a.o_Wv, a.o_bv, a.kh2, a.vh2, n);
    gsync(ctr, 6);
    // S7: out-branch attention partials (last token)
    attn_part_stage<1>(a.q2h, a.kh2, a.vh2, a.pm, a.pl, a.pacc, smem);
    gsync(ctr, 7);
    // S8: combine + Wo + residual(lo_last)
    stage_combine<1>(a.pm, a.pl, a.pacc, Asb);
    gemm_stage<4>(Asb, a.o_Wo, a.o_bo, a.lo1, a.lo_last, 0, n);
    gsync(ctr, 8);
    // S9: LN + fc1 + gelu
    stage_rows_ln_bf16<4>(a.lo1, 0, 1, a.o_lnffn_g, a.o_lnffn_b, Asb, part1, part2);
    gemm_stage<4>(Asb, a.o_fc1_W, a.o_fc1_b, a.g2, nullptr, 1, n);
    gsync(ctr, 9);
    // S10: fc2 + residual(lo1)
    stage_rows_plain_bf16<4>(a.g2, Asb);
    gemm_stage<4>(Asb, a.o_fc2_W, a.o_fc2_b, a.lo2, a.lo1, 0, n);
    gsync(ctr, 10);
    // S11: output head -> y
    stage_rows_plain_bf16<4>(a.lo2, Asb);
    gemm_stage<4>(Asb, a.op_W, a.op_b, a.dout, nullptr, 0, n);
}

extern "C" void kernel_launch(void* const* d_in, const int* in_sizes, int n_in,
                              void* d_out, int out_size, void* d_ws, size_t ws_size,
                              hipStream_t stream)
{
    const float* x        = (const float*)d_in[0];
    const float* state0   = (const float*)d_in[1];
    const float* se_W     = (const float*)d_in[2];
    const float* se_b     = (const float*)d_in[3];
    const float* s_Wq     = (const float*)d_in[4];
    const float* s_bq     = (const float*)d_in[5];
    const float* s_Wk     = (const float*)d_in[6];
    const float* s_bk     = (const float*)d_in[7];
    const float* s_Wv     = (const float*)d_in[8];
    const float* s_bv     = (const float*)d_in[9];
    const float* s_Wo     = (const float*)d_in[10];
    const float* s_bo     = (const float*)d_in[11];
    const float* s_lnq_g  = (const float*)d_in[12];
    const float* s_lnq_b  = (const float*)d_in[13];
    const float* s_lnkv_g = (const float*)d_in[14];
    const float* s_lnkv_b = (const float*)d_in[15];
    const float* s_fc1_W  = (const float*)d_in[16];
    const float* s_fc1_b  = (const float*)d_in[17];
    const float* s_fc2_W  = (const float*)d_in[18];
    const float* s_fc2_b  = (const float*)d_in[19];
    const float* s_lnffn_g= (const float*)d_in[20];
    const float* s_lnffn_b= (const float*)d_in[21];
    const float* s_lnslot_g=(const float*)d_in[22];
    const float* s_lnslot_b=(const float*)d_in[23];
    const float* slot_ctx = (const float*)d_in[24];
    const float* oe_W     = (const float*)d_in[25];
    const float* oe_b     = (const float*)d_in[26];
    const float* o_Wq     = (const float*)d_in[27];
    const float* o_bq     = (const float*)d_in[28];
    const float* o_Wk     = (const float*)d_in[29];
    const float* o_bk     = (const float*)d_in[30];
    const float* o_Wv     = (const float*)d_in[31];
    const float* o_bv     = (const float*)d_in[32];
    const float* o_Wo     = (const float*)d_in[33];
    const float* o_bo     = (const float*)d_in[34];
    const float* o_lnq_g  = (const float*)d_in[35];
    const float* o_lnq_b  = (const float*)d_in[36];
    const float* o_lnkv_g = (const float*)d_in[37];
    const float* o_lnkv_b = (const float*)d_in[38];
    const float* o_fc1_W  = (const float*)d_in[39];
    const float* o_fc1_b  = (const float*)d_in[40];
    const float* o_fc2_W  = (const float*)d_in[41];
    const float* o_fc2_b  = (const float*)d_in[42];
    const float* o_lnffn_g= (const float*)d_in[43];
    const float* o_lnffn_b= (const float*)d_in[44];
    const float* op_W     = (const float*)d_in[45];
    const float* op_b     = (const float*)d_in[46];

    float* ws = (float*)d_ws;
    float* pe   = ws;
    float* cat  = ws + 1048576;
    bf16*  kh2  = (bf16*)(ws + 1048576);
    bf16*  vh2  = (bf16*)(ws + 1048576 + 2105344);
    bf16*  lnbb = (bf16*)(ws + 5259264);
    float* cat2 = ws + 7421952;
    bf16*  kh   = (bf16*)(ws + 7421952);
    bf16*  vh   = (bf16*)(ws + 7421952 + 2105344);
    bf16*  xb   = (bf16*)(ws + 11632640);
    bf16*  lnbb2= (bf16*)(ws + 11632640);
    bf16*  wb   = (bf16*)(ws + 13729792);
    bf16*  seWb = wb;
    bf16*  oeWb = wb + 1048576;
    bf16*  sWkb = wb + 2097152;
    bf16*  sWvb = wb + 3145728;
    bf16*  oWkb = wb + 4194304;
    bf16*  oWvb = wb + 5242880;
    float* sm   = ws + 16875520;
    float* qh_s    = sm + 16384;
    float* lat1    = sm + 49152;
    float* g1      = sm + 81920;
    float* lat2    = sm + 98304;
    float* q2h     = sm + 135232;
    float* lo_last = sm + 143424;
    float* lo1     = sm + 147520;
    float* g2      = sm + 155712;
    float* lo2     = sm + 159808;
    float* pmb     = sm + 163904;
    float* plb     = sm + 164928;
    float* paccb   = sm + 165952;
    float* stateNew= sm + 231488;
    int*   ctr     = (int*)(sm + 262144);   // 12*BARSTRIDE ints
    float* out = (float*)d_out;

    dim3 blk(256);

    // ---- phase 0: conversions + PE + state-row copy + barrier reset ----
    PrepArgs pa;
    pa.cin[0] = x;    pa.cout[0] = xb;
    pa.cin[1] = se_W; pa.cout[1] = seWb;
    pa.cin[2] = oe_W; pa.cout[2] = oeWb;
    pa.cin[3] = s_Wk; pa.cout[3] = sWkb;
    pa.cin[4] = s_Wv; pa.cout[4] = sWvb;
    pa.cin[5] = o_Wk; pa.cout[5] = oWkb;
    pa.cin[6] = o_Wv; pa.cout[6] = oWvb;
    pa.state0 = state0; pa.cat = cat; pa.pe = pe; pa.ctr = ctr;
    prep_kernel<<<11281, blk, 0, stream>>>(pa);

    // ---- phase 1: both embeds, XCD-swizzled ----
    embed_fused_kernel<<<512, blk, 0, stream>>>(
        xb, seWb, oeWb, se_b, oe_b, cat, cat2, pe);

    // ---- phase 2: big LNs + q2/lo_last extraction (cat2 consumed before kv) ----
    ln_fused_kernel<<<8208, blk, 0, stream>>>(cat, cat2, lnbb, lnbb2,
        s_lnkv_g, s_lnkv_b, o_lnkv_g, o_lnkv_b);
    small_ln_gemm_kernel<4><<<256, blk, 0, stream>>>(cat2, TT - 1, LKV,
        o_lnq_g, o_lnq_b, o_Wq, o_bq, q2h);
    copy_lolast_kernel<<<NB, blk, 0, stream>>>(cat2, lo_last);

    // ---- phase 3: all four K/V GEMMs, XCD-swizzled. Overwrites cat/cat2. ----
    kv_fused_kernel<<<1056, blk, 0, stream>>>(
        lnbb, lnbb2, sWkb, sWvb, oWkb, oWvb,
        s_bk, s_bv, o_bk, o_bv, kh, vh, kh2, vh2);

    // ---- phase 4: persistent mega kernel (attn -> gate -> out-branch -> head) ----
    MegaArgs ma;
    ma.state0 = state0; ma.s_lnq_g = s_lnq_g; ma.s_lnq_b = s_lnq_b;
    ma.s_Wq = s_Wq; ma.s_bq = s_bq; ma.qh_s = qh_s;
    ma.kh = kh; ma.vh = vh; ma.pm = pmb; ma.pl = plb; ma.pacc = paccb;
    ma.s_Wo = s_Wo; ma.s_bo = s_bo; ma.lat1 = lat1;
    ma.s_lnffn_g = s_lnffn_g; ma.s_lnffn_b = s_lnffn_b;
    ma.s_fc1_W = s_fc1_W; ma.s_fc1_b = s_fc1_b; ma.g1 = g1;
    ma.s_fc2_W = s_fc2_W; ma.s_fc2_b = s_fc2_b; ma.lat2 = lat2;
    ma.s_lnslot_g = s_lnslot_g; ma.s_lnslot_b = s_lnslot_b; ma.slot_ctx = slot_ctx;
    ma.stateNew = stateNew;
    ma.o_lnkv_g = o_lnkv_g; ma.o_lnkv_b = o_lnkv_b;
    ma.o_Wk = o_Wk; ma.o_bk = o_bk; ma.o_Wv = o_Wv; ma.o_bv = o_bv;
    ma.kh2 = kh2; ma.vh2 = vh2; ma.q2h = q2h;
    ma.o_Wo = o_Wo; ma.o_bo = o_bo; ma.lo_last = lo_last; ma.lo1 = lo1;
    ma.o_lnffn_g = o_lnffn_g; ma.o_lnffn_b = o_lnffn_b;
    ma.o_fc1_W = o_fc1_W; ma.o_fc1_b = o_fc1_b; ma.g2 = g2;
    ma.o_fc2_W = o_fc2_W; ma.o_fc2_b = o_fc2_b; ma.lo2 = lo2;
    ma.op_W = op_W; ma.op_b = op_b; ma.dout = out; ma.ctr = ctr;
    mega_kernel<<<GRID_N, blk, 0, stream>>>(ma);
}